// Round 6
// baseline (1098.572 us; speedup 1.0000x reference)
//
#include <hip/hip_runtime.h>
#include <hip/hip_bf16.h>
#include <math.h>

typedef unsigned short u16;
typedef __attribute__((ext_vector_type(8))) short bf16x8;
typedef __attribute__((ext_vector_type(4))) float f32x4;

#define B_    2048
#define V_    4096
#define L_    10
#define H_    512
#define E_    256
#define META_ 15
#define H4_   2048
#define KT_   1536                 // tripled K  (A: hi|lo|hi,  B: hi|hi|lo)
#define NT24  24                   // K-tiles of 64
#define TSZ   16384                // elems per 256x64 packed tile
#define EOS_  0
#define INIT_LEN_ (L_ + 1)

// ---- output layout (flat f32, reference return order) ----
constexpr size_t OUT_SL  = (size_t)B_ * (L_ + 1) * V_;
constexpr size_t OUT_ENT = OUT_SL + B_;
constexpr size_t OUT_EMB = OUT_ENT + 1;
constexpr size_t OUT_SP  = OUT_EMB + (size_t)B_ * L_ * E_;

// ---- workspace layout ----
constexpr size_t WS_E2G     = 0;                              // [V,4H] f32
constexpr size_t WS_LOGITS  = WS_E2G    + (size_t)V_ * H4_;   // [B,V] f32
constexpr size_t WS_G       = WS_LOGITS + (size_t)B_ * V_;    // [B,4H] f32
constexpr size_t WS_C       = WS_G      + (size_t)B_ * H4_;   // [B,H] f32
constexpr size_t WS_F32_END = WS_C      + (size_t)B_ * H_;
constexpr size_t U_B6       = 0;                              // [24 panels][24 kt][16384] u16
constexpr size_t U_HP       = U_B6 + (size_t)6144 * KT_;      // [8 panels][24 kt][16384] u16
constexpr size_t U_END      = U_HP + (size_t)B_ * KT_;

__device__ __forceinline__ u16 f2bf(float f) {
    union { __hip_bfloat16 b; u16 u; } cv; cv.b = __float2bfloat16(f); return cv.u;
}
__device__ __forceinline__ float bf2f(u16 u) {
    union { u16 u; __hip_bfloat16 b; } cv; cv.u = u; return __bfloat162float(cv.b);
}
__device__ __forceinline__ void gld16(const u16* g, void* l) {
    __builtin_amdgcn_global_load_lds(
        (const __attribute__((address_space(1))) unsigned int*)g,
        (__attribute__((address_space(3))) unsigned int*)l, 16, 0, 0);
}

// packed tile-linear addressing: 256-row panels, 64-K tiles,
// within tile: [s = (k>>3)&7][row][e = k&7]   (16384 elems / tile)
__device__ __forceinline__ size_t pk_addr(int row256, int k) {
    return (size_t)(k >> 6) * TSZ + (size_t)((k >> 3) & 7) * 2048 +
           (size_t)row256 * 8 + (k & 7);
}
__device__ __forceinline__ size_t b6_addr(int col, int k) {
    return (size_t)(col >> 8) * (NT24 * TSZ) + pk_addr(col & 255, k);
}
__device__ __forceinline__ size_t a6_addr(int b, int k) {
    return (size_t)(b >> 8) * (NT24 * TSZ) + pk_addr(b & 255, k);
}

// ---------------------------------------------------------------------------
// 8-phase pipelined 256x256 bf16 NT GEMM over K=1536, BK=64, 2 LDS buffers
// (128 KB), counted vmcnt(4) at tile boundaries only.  8 waves (2M x 4N).
// Per K-tile: 4 phases {ds_read subtile || stage 2 gld16 -> barrier ->
// 16 MFMA -> barrier}.  Stage targets the region whose reads drained in the
// previous phase (WAR-safe); reads of tile t are covered by the end-of-(t-1)
// vmcnt(4)+barrier (RAW-safe; FIFO: 12 in flight, oldest 8 = tile t).
// col panels < 8 -> G (ldc=4H, raw); panels >= 8 -> LOGITS (ldc=V) + bias.
// ---------------------------------------------------------------------------
__global__ __launch_bounds__(512, 2)
void gemmP(const u16* __restrict__ A6, const u16* __restrict__ B6,
           float* __restrict__ G, float* __restrict__ LOG,
           const float* __restrict__ bias, int xoff)
{
    __shared__ u16 As[2][TSZ];
    __shared__ u16 Bs[2][TSZ];
    const int tid  = threadIdx.x;
    const int lane = tid & 63;
    const int wave = tid >> 6;
    const int wr = wave >> 2, wc = wave & 3;      // 2M x 4N
    const int fr = lane & 15, kq = lane >> 4;

    // bijective XCD-chunked swizzle (nwg divisible by 8)
    const int nwg = gridDim.x * gridDim.y;
    const int bid = blockIdx.y * gridDim.x + blockIdx.x;
    const int w   = (bid & 7) * (nwg >> 3) + (bid >> 3);
    const int colb = (w >> 3) + xoff;
    const int rowp = w & 7;
    const int row0 = rowp * 256;
    const int col0 = colb * 256;

    const u16* AsrcP = A6 + (size_t)rowp * (NT24 * TSZ);
    const u16* BsrcP = B6 + (size_t)colb * (NT24 * TSZ);

    // fragment element bases within a tile: addr = base + KK*8192 + (MH*4+m)*128
    const int aoff = kq * 2048 + (wr * 128 + fr) * 8;
    const int boff = kq * 2048 + (wc * 64 + fr) * 8;

    f32x4 acc[8][4] = {};
    bf16x8 aR[4], bR[4];

#define STG(dst, src) do {                                     \
    gld16((src) + tid * 8,        (dst) + tid * 8);            \
    gld16((src) + tid * 8 + 4096, (dst) + tid * 8 + 4096); } while (0)
#define BAR asm volatile("s_barrier" ::: "memory")
#define RD_A(CUR, KK, MH)                                                     \
    _Pragma("unroll")                                                         \
    for (int m_ = 0; m_ < 4; ++m_)                                            \
        aR[m_] = *(const bf16x8*)(&As[CUR][0] + aoff + (KK) * 8192 + (MH) * 512 + m_ * 128);
#define RD_B(CUR, KK)                                                         \
    _Pragma("unroll")                                                         \
    for (int n_ = 0; n_ < 4; ++n_)                                            \
        bR[n_] = *(const bf16x8*)(&Bs[CUR][0] + boff + (KK) * 8192 + n_ * 128);
#define MM(MH)                                                                \
    __builtin_amdgcn_s_setprio(1);                                            \
    _Pragma("unroll")                                                         \
    for (int m_ = 0; m_ < 4; ++m_)                                            \
        _Pragma("unroll")                                                     \
        for (int n_ = 0; n_ < 4; ++n_)                                        \
            acc[(MH) * 4 + m_][n_] = __builtin_amdgcn_mfma_f32_16x16x32_bf16( \
                aR[m_], bR[n_], acc[(MH) * 4 + m_][n_], 0, 0, 0);             \
    __builtin_amdgcn_s_setprio(0);

#define TILE(T, CUR, OTH) do {                                                \
    /* phase 0: KK=0, m0-3 */                                                 \
    RD_B(CUR, 0); RD_A(CUR, 0, 0);                                            \
    if ((T) + 1 < NT24) STG(&Bs[OTH][8192], BsrcP + (size_t)((T) + 1) * TSZ + 8192); \
    BAR; MM(0); BAR;                                                          \
    /* phase 1: KK=0, m4-7 */                                                 \
    RD_A(CUR, 0, 1);                                                          \
    if ((T) + 1 < NT24) STG(&As[OTH][8192], AsrcP + (size_t)((T) + 1) * TSZ + 8192); \
    BAR; MM(1); BAR;                                                          \
    /* phase 2: KK=1, m0-3 */                                                 \
    RD_B(CUR, 1); RD_A(CUR, 1, 0);                                            \
    if ((T) + 2 < NT24) STG(&Bs[CUR][0], BsrcP + (size_t)((T) + 2) * TSZ);    \
    BAR; MM(0); BAR;                                                          \
    /* phase 3: KK=1, m4-7 */                                                 \
    RD_A(CUR, 1, 1);                                                          \
    if ((T) + 2 < NT24) STG(&As[CUR][0], AsrcP + (size_t)((T) + 2) * TSZ);    \
    BAR; MM(1);                                                               \
    if ((T) < NT24 - 2)                                                       \
        asm volatile("s_waitcnt vmcnt(4)\ns_barrier" ::: "memory");           \
    else if ((T) == NT24 - 2)                                                 \
        asm volatile("s_waitcnt vmcnt(0)\ns_barrier" ::: "memory");           \
  } while (0)

    // prologue: tile0 fully (8 loads) + tile1 s03 halves (4 loads)
    STG(&Bs[0][0],    BsrcP);
    STG(&As[0][0],    AsrcP);
    STG(&Bs[0][8192], BsrcP + 8192);
    STG(&As[0][8192], AsrcP + 8192);
    STG(&Bs[1][0],    BsrcP + TSZ);
    STG(&As[1][0],    AsrcP + TSZ);
    asm volatile("s_waitcnt vmcnt(4)\ns_barrier" ::: "memory");

    for (int tt = 0; tt < NT24; tt += 2) {
        TILE(tt,     0, 1);
        TILE(tt + 1, 1, 0);
    }
#undef TILE
#undef MM
#undef RD_B
#undef RD_A
#undef BAR
#undef STG

    // epilogue
    const bool isG = (col0 < H4_);
    float* Cb      = isG ? G : LOG;
    const int ldc  = isG ? H4_ : V_;
    const int cbase = (isG ? col0 : col0 - H4_) + wc * 64 + fr;
#pragma unroll
    for (int m = 0; m < 8; ++m) {
#pragma unroll
        for (int r = 0; r < 4; ++r) {
            const int grow = row0 + wr * 128 + m * 16 + kq * 4 + r;
            float* cp = Cb + (size_t)grow * ldc + cbase;
#pragma unroll
            for (int n = 0; n < 4; ++n) {
                float v = acc[m][n][r];
                if (!isG) v += bias[cbase + n * 16];
                cp[n * 16] = v;
            }
        }
    }
}

// ---------------------------------------------------------------------------
// repack W_hh [2048][512] f32 -> B6 panels 0-7 (hi|hi|lo over K)
__global__ __launch_bounds__(256)
void repack_whh(const float* __restrict__ W_hh, u16* __restrict__ B6)
{
    const int c0 = blockIdx.x * 32, k0 = blockIdx.y * 64;
    const int cc = threadIdx.x & 31, kg = threadIdx.x >> 5;
    const int col = c0 + cc;
#pragma unroll
    for (int e = 0; e < 8; ++e) {
        const int kp = k0 + kg * 8 + e;               // 0..511
        const float v = W_hh[(size_t)col * H_ + kp];
        const u16 h = f2bf(v);
        const u16 l = f2bf(v - bf2f(h));
        B6[b6_addr(col, kp)]          = h;
        B6[b6_addr(col, 512 + kp)]    = h;
        B6[b6_addr(col, 1024 + kp)]   = l;
    }
}

// repack W_out [512][4096] f32 (transposed) -> B6 panels 8-23
__global__ __launch_bounds__(256)
void repack_wout(const float* __restrict__ W_out, u16* __restrict__ B6)
{
    __shared__ float t[64][33];
    const int c0 = blockIdx.x * 32, k0 = blockIdx.y * 64;
    const int x = threadIdx.x & 31, y = threadIdx.x >> 5;   // 32 x 8
    for (int yy = y; yy < 64; yy += 8)
        t[yy][x] = W_out[(size_t)(k0 + yy) * V_ + c0 + x];
    __syncthreads();
    const int cc = threadIdx.x & 31, kg = threadIdx.x >> 5;
    const int col = 2048 + c0 + cc;
#pragma unroll
    for (int e = 0; e < 8; ++e) {
        const int kp = k0 + kg * 8 + e;
        const float v = t[kp - k0][cc];
        const u16 h = f2bf(v);
        const u16 l = f2bf(v - bf2f(h));
        B6[b6_addr(col, kp)]        = h;
        B6[b6_addr(col, 512 + kp)]  = h;
        B6[b6_addr(col, 1024 + kp)] = l;
    }
}

// ---------------------------------------------------------------------------
// 128^2 2-barrier MFMA GEMM kept for the one-time E2G build
__global__ __launch_bounds__(256)
void gemm_e2g(const u16* __restrict__ Ah, const u16* __restrict__ Al,
              const u16* __restrict__ Bh, const u16* __restrict__ Bl,
              float* __restrict__ C0, int K,
              const float* __restrict__ bias0, const float* __restrict__ bias1)
{
    __shared__ u16 As[2][128][32];
    __shared__ u16 Bs[2][128][32];
    const int tid  = threadIdx.x;
    const int lane = tid & 63;
    const int wave = tid >> 6;
    const int wm = wave >> 1, wn = wave & 1;
    const int nwg  = gridDim.x * gridDim.y;
    const int bid  = blockIdx.y * gridDim.x + blockIdx.x;
    const int w    = (bid & 7) * (nwg >> 3) + (bid >> 3);
    const int colb = w / gridDim.y;
    const int rowb = w % gridDim.y;
    const int col0 = colb * 128;
    const int row0 = rowb * 128;

    const int srow = tid >> 2;
    const int scol = (tid & 3) * 8;
    const size_t aoff = (size_t)(row0 + srow) * K + scol;
    const size_t boff = (size_t)(col0 + srow) * K + scol;
    const size_t skip = (size_t)64 * K;

    u16* lA0 = &As[0][0][0];
    u16* lA1 = &As[1][0][0];
    u16* lB0 = &Bs[0][0][0];
    u16* lB1 = &Bs[1][0][0];
    const int d0 = tid * 8;
    const int d1 = d0 + 2048;

    f32x4 acc[4][4] = {};
    const int fr = lane & 15;
    const int kq = lane >> 4;

    for (int k0 = 0; k0 < K; k0 += 32) {
        __syncthreads();
        gld16(Ah + aoff + k0,        lA0 + d0);
        gld16(Ah + aoff + k0 + skip, lA0 + d1);
        gld16(Al + aoff + k0,        lA1 + d0);
        gld16(Al + aoff + k0 + skip, lA1 + d1);
        gld16(Bh + boff + k0,        lB0 + d0);
        gld16(Bh + boff + k0 + skip, lB0 + d1);
        gld16(Bl + boff + k0,        lB1 + d0);
        gld16(Bl + boff + k0 + skip, lB1 + d1);
        __syncthreads();

        bf16x8 ah[4], al[4], bh[4], bl[4];
#pragma unroll
        for (int i = 0; i < 4; ++i) {
            ah[i] = *(const bf16x8*)&As[0][wm * 64 + i * 16 + fr][kq * 8];
            al[i] = *(const bf16x8*)&As[1][wm * 64 + i * 16 + fr][kq * 8];
            bh[i] = *(const bf16x8*)&Bs[0][wn * 64 + i * 16 + fr][kq * 8];
            bl[i] = *(const bf16x8*)&Bs[1][wn * 64 + i * 16 + fr][kq * 8];
        }
#pragma unroll
        for (int mi = 0; mi < 4; ++mi)
#pragma unroll
            for (int ni = 0; ni < 4; ++ni) {
                acc[mi][ni] = __builtin_amdgcn_mfma_f32_16x16x32_bf16(ah[mi], bh[ni], acc[mi][ni], 0, 0, 0);
                acc[mi][ni] = __builtin_amdgcn_mfma_f32_16x16x32_bf16(ah[mi], bl[ni], acc[mi][ni], 0, 0, 0);
                acc[mi][ni] = __builtin_amdgcn_mfma_f32_16x16x32_bf16(al[mi], bh[ni], acc[mi][ni], 0, 0, 0);
            }
    }

    const int cc0 = col0 + wn * 64 + fr;
#pragma unroll
    for (int mi = 0; mi < 4; ++mi) {
#pragma unroll
        for (int r = 0; r < 4; ++r) {
            const int grow = row0 + wm * 64 + mi * 16 + kq * 4 + r;
            float* cp = C0 + (size_t)grow * H4_ + cc0;
#pragma unroll
            for (int ni = 0; ni < 4; ++ni)
                cp[ni * 16] = acc[mi][ni][r] + bias0[cc0 + ni * 16] + bias1[cc0 + ni * 16];
        }
    }
}

// ---------------------------------------------------------------------------
// elementwise f32 -> bf16 hi/lo split (emb, W_ih for E2G build)
__global__ __launch_bounds__(256)
void split_mat(const float* __restrict__ X, u16* __restrict__ hi,
               u16* __restrict__ lo)
{
    const int i = blockIdx.x * 256 + threadIdx.x;
    float4 v = ((const float4*)X)[i];
    const u16 h0 = f2bf(v.x), h1 = f2bf(v.y), h2 = f2bf(v.z), h3 = f2bf(v.w);
    ((ushort4*)hi)[i] = make_ushort4(h0, h1, h2, h3);
    ((ushort4*)lo)[i] = make_ushort4(f2bf(v.x - bf2f(h0)), f2bf(v.y - bf2f(h1)),
                                     f2bf(v.z - bf2f(h2)), f2bf(v.w - bf2f(h3)));
}

// h0 = hidden_state @ W_in + b_in -> packed A6 slices; c0 = 0
__global__ __launch_bounds__(256)
void h0_kernel(const float* __restrict__ hs, const float* __restrict__ W_in,
               const float* __restrict__ b_in, u16* __restrict__ hp,
               float* __restrict__ c)
{
    const int idx = blockIdx.x * 256 + threadIdx.x;
    const int b = idx >> 9, j = idx & 511;
    float acc = b_in[j];
#pragma unroll
    for (int e = 0; e < META_; ++e)
        acc = fmaf(hs[b * META_ + e], W_in[e * H_ + j], acc);
    const u16 hh = f2bf(acc);
    const u16 hl = f2bf(acc - bf2f(hh));
    hp[a6_addr(b, j)]        = hh;
    hp[a6_addr(b, 512 + j)]  = hl;
    hp[a6_addr(b, 1024 + j)] = hh;
    c[idx] = 0.f;
}

__global__ __launch_bounds__(256)
void init_outputs(float* __restrict__ out, int* __restrict__ tok,
                  int* __restrict__ sl, float* __restrict__ ents)
{
    const int tid = blockIdx.x * 256 + threadIdx.x;
    {
        const int b = tid >> 10;
        const int q = tid & 1023;
        float4 z = make_float4(0.f, 0.f, 0.f, 0.f);
        if (q == 0) z.x = 1.0f;           // SOS = 0
        ((float4*)out)[(size_t)b * ((L_ + 1) * V_ / 4) + q] = z;
    }
    for (size_t t = tid; t < (size_t)B_ * V_; t += (size_t)gridDim.x * 256)
        out[OUT_SP + t] = 0.f;
    if (tid < B_) { tok[tid] = 0; sl[tid] = INIT_LEN_; ents[tid] = 0.f; }
}

// LSTM pointwise: gates = G + E2G[tok]; writes packed A6 h-slices, embeds out
__global__ __launch_bounds__(256)
void lstm_cell(const float* __restrict__ G, const float* __restrict__ e2g,
               u16* __restrict__ hp, float* __restrict__ c,
               const float* __restrict__ embedding, const int* __restrict__ tok,
               float* __restrict__ out, int step)
{
    const int idx = blockIdx.x * 256 + threadIdx.x;   // B*H
    const int b = idx >> 9, j = idx & 511;
    const size_t g0 = (size_t)b * H4_;
    const size_t e0 = (size_t)tok[b] * H4_;
    const float ig = G[g0 + j]          + e2g[e0 + j];
    const float fg = G[g0 + H_ + j]     + e2g[e0 + H_ + j];
    const float gg = G[g0 + 2 * H_ + j] + e2g[e0 + 2 * H_ + j];
    const float og = G[g0 + 3 * H_ + j] + e2g[e0 + 3 * H_ + j];
    const float si = 1.f / (1.f + expf(-ig));
    const float sf = 1.f / (1.f + expf(-fg));
    const float so = 1.f / (1.f + expf(-og));
    const float cn = sf * c[idx] + si * tanhf(gg);
    c[idx] = cn;
    const float hv = so * tanhf(cn);
    const u16 hh = f2bf(hv);
    const u16 hl = f2bf(hv - bf2f(hh));
    hp[a6_addr(b, j)]        = hh;
    hp[a6_addr(b, 512 + j)]  = hl;
    hp[a6_addr(b, 1024 + j)] = hh;
    if (j < E_)
        out[OUT_EMB + ((size_t)b * L_ + step) * E_ + j] =
            embedding[(size_t)tok[b] * E_ + j];
}

// per-row: entropy (LSE), argmax(logits+gumbel), one-hot write, state update
__global__ __launch_bounds__(256)
void softmax_step(const float* __restrict__ logits, const float* __restrict__ gumbel,
                  float* __restrict__ out, int* __restrict__ tok,
                  int* __restrict__ sl, float* __restrict__ ents, int step)
{
    const int b   = blockIdx.x;
    const int tid = threadIdx.x;
    const float* lrow = logits + (size_t)b * V_;
    const float* grow = gumbel + ((size_t)step * B_ + b) * V_;
    __shared__ float lsm[V_];
    __shared__ float red_m[4], red_bv[4], red_s[4], red_t[4];
    __shared__ int   red_bi[4];
    __shared__ float s_M;
    __shared__ int   s_bi;

    float m = -3.4e38f, bv = -3.4e38f;
    int bi = 0x7fffffff;
    for (int q = tid; q < V_ / 4; q += 256) {
        float4 l4 = ((const float4*)lrow)[q];
        float4 g4 = ((const float4*)grow)[q];
        ((float4*)lsm)[q] = l4;
        m = fmaxf(m, fmaxf(fmaxf(l4.x, l4.y), fmaxf(l4.z, l4.w)));
        float p; const int i4 = q * 4;
        p = l4.x + g4.x; if (p > bv) { bv = p; bi = i4; }
        p = l4.y + g4.y; if (p > bv) { bv = p; bi = i4 + 1; }
        p = l4.z + g4.z; if (p > bv) { bv = p; bi = i4 + 2; }
        p = l4.w + g4.w; if (p > bv) { bv = p; bi = i4 + 3; }
    }
#pragma unroll
    for (int off = 32; off > 0; off >>= 1) {
        m = fmaxf(m, __shfl_down(m, off));
        float obv = __shfl_down(bv, off);
        int   obi = __shfl_down(bi, off);
        if (obv > bv || (obv == bv && obi < bi)) { bv = obv; bi = obi; }
    }
    const int wave = tid >> 6, lane = tid & 63;
    if (lane == 0) { red_m[wave] = m; red_bv[wave] = bv; red_bi[wave] = bi; }
    __syncthreads();
    if (tid == 0) {
        m = red_m[0]; bv = red_bv[0]; bi = red_bi[0];
        for (int w = 1; w < 4; ++w) {
            m = fmaxf(m, red_m[w]);
            if (red_bv[w] > bv || (red_bv[w] == bv && red_bi[w] < bi)) {
                bv = red_bv[w]; bi = red_bi[w];
            }
        }
        s_M = m; s_bi = bi;
    }
    __syncthreads();
    const float M = s_M;
    const int amax = s_bi;

    float s = 0.f, t = 0.f;
    for (int q = tid; q < V_; q += 256) {
        const float l = lsm[q];
        const float e = __expf(l - M);
        s += e; t += e * l;
    }
#pragma unroll
    for (int off = 32; off > 0; off >>= 1) {
        s += __shfl_down(s, off);
        t += __shfl_down(t, off);
    }
    if (lane == 0) { red_s[wave] = s; red_t[wave] = t; }

    float* orow = out + ((size_t)b * (L_ + 1) + step + 1) * V_;
    const float4 z4 = make_float4(0.f, 0.f, 0.f, 0.f);
    for (int q = tid; q < V_ / 4; q += 256) ((float4*)orow)[q] = z4;
    __syncthreads();
    if (tid == 0) {
        const float ss = red_s[0] + red_s[1] + red_s[2] + red_s[3];
        const float tt = red_t[0] + red_t[1] + red_t[2] + red_t[3];
        const float ent = (M + logf(ss)) - tt / ss;
        ents[b] += ent;
        orow[amax] = 1.0f;
        tok[b] = amax;
        if (amax == EOS_ && sl[b] == INIT_LEN_) sl[b] = step + 2;
    }
}

__global__ __launch_bounds__(256)
void finalize(const int* __restrict__ sl, const float* __restrict__ ents,
              float* __restrict__ out)
{
    const int tid = threadIdx.x;
    float s = 0.f;
    for (int b = tid; b < B_; b += 256) {
        s += ents[b];
        out[OUT_SL + b] = (float)sl[b];
    }
    __shared__ float red[4];
#pragma unroll
    for (int off = 32; off > 0; off >>= 1) s += __shfl_down(s, off);
    if ((tid & 63) == 0) red[tid >> 6] = s;
    __syncthreads();
    if (tid == 0)
        out[OUT_ENT] = (red[0] + red[1] + red[2] + red[3]) / (float)B_ / (float)L_;
}

// ---------------------------------------------------------------------------
extern "C" void kernel_launch(void* const* d_in, const int* in_sizes, int n_in,
                              void* d_out, int out_size, void* d_ws, size_t ws_size,
                              hipStream_t stream)
{
    const float* hidden    = (const float*)d_in[0];
    const float* W_in      = (const float*)d_in[1];
    const float* b_in      = (const float*)d_in[2];
    const float* embedding = (const float*)d_in[3];
    const float* W_ih      = (const float*)d_in[4];
    const float* W_hh      = (const float*)d_in[5];
    const float* b_ih      = (const float*)d_in[6];
    const float* b_hh      = (const float*)d_in[7];
    const float* W_out     = (const float*)d_in[8];
    const float* b_out     = (const float*)d_in[9];
    const float* gumbel    = (const float*)d_in[10];
    float* out = (float*)d_out;

    float* ws    = (float*)d_ws;
    float* E2G   = ws + WS_E2G;
    float* logit = ws + WS_LOGITS;
    float* G     = ws + WS_G;
    float* c     = ws + WS_C;
    u16*   wsu   = (u16*)(ws + WS_F32_END);
    u16* B6      = wsu + U_B6;
    u16* hp      = wsu + U_HP;
    int* tok     = (int*)(wsu + U_END);
    int* sl      = tok + B_;
    float* ents  = (float*)(sl + B_);
    // emb/wih bf16 splits overlay the LOGITS region (dead after E2G build)
    u16* emb_hi  = (u16*)logit;
    u16* emb_lo  = emb_hi + (size_t)V_ * E_;
    u16* wih_hi  = emb_lo + (size_t)V_ * E_;
    u16* wih_lo  = wih_hi + (size_t)H4_ * E_;

    // ---- one-time per call ----
    repack_whh<<<dim3(H4_ / 32, H_ / 64), 256, 0, stream>>>(W_hh, B6);
    repack_wout<<<dim3(V_ / 32, H_ / 64), 256, 0, stream>>>(W_out, B6);
    split_mat<<<(V_ * E_ / 4) / 256, 256, 0, stream>>>(embedding, emb_hi, emb_lo);
    split_mat<<<(H4_ * E_ / 4) / 256, 256, 0, stream>>>(W_ih, wih_hi, wih_lo);
    h0_kernel<<<(B_ * H_) / 256, 256, 0, stream>>>(hidden, W_in, b_in, hp, c);
    init_outputs<<<(B_ * V_ / 4) / 256, 256, 0, stream>>>(out, tok, sl, ents);
    // E2G = embedding @ W_ih^T + b_ih + b_hh   [V, 4H]
    gemm_e2g<<<dim3(H4_ / 128, V_ / 128), 256, 0, stream>>>(
        emb_hi, emb_lo, wih_hi, wih_lo, E2G, E_, b_ih, b_hh);
    // G0 = h0 @ W_hh^T  (panels 0-7 only)
    gemmP<<<dim3(8, 8), 512, 0, stream>>>(hp, B6, G, logit, b_out, 0);

    for (int i = 0; i < L_; ++i) {
        lstm_cell<<<(B_ * H_) / 256, 256, 0, stream>>>(G, E2G, hp, c,
                                                       embedding, tok, out, i);
        if (i < L_ - 1) {
            // [G_{i+1} | logits_i] = h_{i+1} @ [W_hh | WoutT]^T  (24 panels)
            gemmP<<<dim3(24, 8), 512, 0, stream>>>(hp, B6, G, logit, b_out, 0);
        } else {
            // logits only (panels 8-23)
            gemmP<<<dim3(16, 8), 512, 0, stream>>>(hp, B6, G, logit, b_out, 8);
        }
        softmax_step<<<B_, 256, 0, stream>>>(logit, gumbel, out, tok, sl, ents, i);
    }
    finalize<<<1, 256, 0, stream>>>(sl, ents, out);
}

// Round 7
// 1055.138 us; speedup vs baseline: 1.0412x; 1.0412x over previous
//
#include <hip/hip_runtime.h>
#include <hip/hip_bf16.h>
#include <math.h>

typedef unsigned short u16;
typedef __attribute__((ext_vector_type(8))) short bf16x8;
typedef __attribute__((ext_vector_type(4))) float f32x4;

#define B_    2048
#define V_    4096
#define L_    10
#define H_    512
#define E_    256
#define META_ 15
#define H4_   2048
#define W6_   (H4_ + V_)          // 6144 combined B rows (W_hh | WoutT)
#define EOS_  0
#define INIT_LEN_ (L_ + 1)

// ---- output layout (flat float32, reference return order) ----
constexpr size_t OUT_SL  = (size_t)B_ * (L_ + 1) * V_;
constexpr size_t OUT_ENT = OUT_SL + B_;
constexpr size_t OUT_EMB = OUT_ENT + 1;
constexpr size_t OUT_SP  = OUT_EMB + (size_t)B_ * L_ * E_;

// ---- workspace layout ----
// f32: E2G [V,4H] | SCRATCH (partials + pre-loop emb/wih splits) | G [B,4H] | c [B,H]
// u16: w6_hi/lo [6144,512] | h_hi/lo [B,H]
constexpr size_t WS_E2G     = 0;
constexpr size_t WS_SCR     = WS_E2G + (size_t)V_ * H4_;     // >= B*V floats
constexpr size_t WS_G       = WS_SCR + (size_t)B_ * V_;
constexpr size_t WS_C       = WS_G   + (size_t)B_ * H4_;
constexpr size_t WS_F32_END = WS_C   + (size_t)B_ * H_;
constexpr size_t U_W6_HI    = 0;
constexpr size_t U_W6_LO    = U_W6_HI + (size_t)W6_ * H_;
constexpr size_t U_HHI      = U_W6_LO + (size_t)W6_ * H_;
constexpr size_t U_HLO      = U_HHI   + (size_t)B_ * H_;
constexpr size_t U_END      = U_HLO   + (size_t)B_ * H_;

__device__ __forceinline__ u16 f2bf(float f) {
    union { __hip_bfloat16 b; u16 u; } cv; cv.b = __float2bfloat16(f); return cv.u;
}
__device__ __forceinline__ float bf2f(u16 u) {
    union { u16 u; __hip_bfloat16 b; } cv; cv.u = u; return __bfloat162float(cv.b);
}

__device__ __forceinline__ void gld16(const u16* g, void* l) {
    __builtin_amdgcn_global_load_lds(
        (const __attribute__((address_space(1))) unsigned int*)g,
        (__attribute__((address_space(3))) unsigned int*)l, 16, 0, 0);
}

// ---------------------------------------------------------------------------
// bf16x3 split MFMA NT GEMM (round-3 structure).  128x128 tile, BK=32, 4 waves.
// EPI 0: C0[row,col] (ldc=4H) += bias0[col] + bias1[col]          (E2G build)
// EPI 1: col<4H -> C0=G raw;  col>=4H -> softmax PARTIALS to part:
//        per (row, 64-col group): {max_l, sum_e, sum_le, best(l+gum), idx}
// ---------------------------------------------------------------------------
template <int EPI>
__global__ __launch_bounds__(256)
void gemm3(const u16* __restrict__ Ah, const u16* __restrict__ Al,
           const u16* __restrict__ Bh, const u16* __restrict__ Bl,
           float* __restrict__ C0, float* __restrict__ part, int K,
           const float* __restrict__ bias0, const float* __restrict__ bias1,
           const float* __restrict__ gumbel, int step, int xoff)
{
    __shared__ u16 As[2][128][32];
    __shared__ u16 Bs[2][128][32];
    const int tid  = threadIdx.x;
    const int lane = tid & 63;
    const int wave = tid >> 6;
    const int wm = wave >> 1, wn = wave & 1;

    // bijective XCD-chunked swizzle, column-clustered
    const int nwg  = gridDim.x * gridDim.y;
    const int bid  = blockIdx.y * gridDim.x + blockIdx.x;
    const int w    = (bid & 7) * (nwg >> 3) + (bid >> 3);
    const int colb = w / gridDim.y + xoff;
    const int rowb = w % gridDim.y;
    const int col0 = colb * 128;
    const int row0 = rowb * 128;

    const int srow = tid >> 2;
    const int scol = (tid & 3) * 8;
    const size_t aoff = (size_t)(row0 + srow) * K + scol;
    const size_t boff = (size_t)(col0 + srow) * K + scol;
    const size_t skip = (size_t)64 * K;

    u16* lA0 = &As[0][0][0];
    u16* lA1 = &As[1][0][0];
    u16* lB0 = &Bs[0][0][0];
    u16* lB1 = &Bs[1][0][0];
    const int d0 = tid * 8;
    const int d1 = d0 + 2048;

    f32x4 acc[4][4] = {};
    const int fr = lane & 15;
    const int kq = lane >> 4;

    for (int k0 = 0; k0 < K; k0 += 32) {
        __syncthreads();
        gld16(Ah + aoff + k0,        lA0 + d0);
        gld16(Ah + aoff + k0 + skip, lA0 + d1);
        gld16(Al + aoff + k0,        lA1 + d0);
        gld16(Al + aoff + k0 + skip, lA1 + d1);
        gld16(Bh + boff + k0,        lB0 + d0);
        gld16(Bh + boff + k0 + skip, lB0 + d1);
        gld16(Bl + boff + k0,        lB1 + d0);
        gld16(Bl + boff + k0 + skip, lB1 + d1);
        __syncthreads();

        bf16x8 ah[4], al[4], bh[4], bl[4];
#pragma unroll
        for (int i = 0; i < 4; ++i) {
            ah[i] = *(const bf16x8*)&As[0][wm * 64 + i * 16 + fr][kq * 8];
            al[i] = *(const bf16x8*)&As[1][wm * 64 + i * 16 + fr][kq * 8];
            bh[i] = *(const bf16x8*)&Bs[0][wn * 64 + i * 16 + fr][kq * 8];
            bl[i] = *(const bf16x8*)&Bs[1][wn * 64 + i * 16 + fr][kq * 8];
        }
#pragma unroll
        for (int mi = 0; mi < 4; ++mi)
#pragma unroll
            for (int ni = 0; ni < 4; ++ni) {
                acc[mi][ni] = __builtin_amdgcn_mfma_f32_16x16x32_bf16(ah[mi], bh[ni], acc[mi][ni], 0, 0, 0);
                acc[mi][ni] = __builtin_amdgcn_mfma_f32_16x16x32_bf16(ah[mi], bl[ni], acc[mi][ni], 0, 0, 0);
                acc[mi][ni] = __builtin_amdgcn_mfma_f32_16x16x32_bf16(al[mi], bh[ni], acc[mi][ni], 0, 0, 0);
            }
    }

    // C/D layout: col = lane&15, row = (lane>>4)*4 + reg
    if (EPI == 0 || col0 < H4_) {
        const int cc0 = col0 + wn * 64 + fr;
#pragma unroll
        for (int mi = 0; mi < 4; ++mi) {
#pragma unroll
            for (int r = 0; r < 4; ++r) {
                const int grow = row0 + wm * 64 + mi * 16 + kq * 4 + r;
                float* cp = C0 + (size_t)grow * H4_ + cc0;
#pragma unroll
                for (int ni = 0; ni < 4; ++ni) {
                    float v = acc[mi][ni][r];
                    if (EPI == 0) v += bias0[cc0 + ni * 16] + bias1[cc0 + ni * 16];
                    cp[ni * 16] = v;
                }
            }
        }
    } else {
        // logits panels: per-row softmax partials over this wave's 64 cols
        const int vbase = (col0 - H4_) + wn * 64 + fr;          // global v col
        const int grp   = ((col0 - H4_) >> 6) + wn;             // 0..63
        const float* gum = gumbel + (size_t)step * B_ * V_;
#pragma unroll
        for (int mi = 0; mi < 4; ++mi) {
#pragma unroll
            for (int r = 0; r < 4; ++r) {
                const int grow = row0 + wm * 64 + mi * 16 + kq * 4 + r;
                const float* gr = gum + (size_t)grow * V_ + vbase;
                float l[4], gv[4];
#pragma unroll
                for (int ni = 0; ni < 4; ++ni) l[ni] = acc[mi][ni][r] + bias0[vbase + ni * 16];
#pragma unroll
                for (int ni = 0; ni < 4; ++ni) gv[ni] = gr[ni * 16];
                float lm = fmaxf(fmaxf(l[0], l[1]), fmaxf(l[2], l[3]));
#pragma unroll
                for (int d = 1; d < 16; d <<= 1) lm = fmaxf(lm, __shfl_xor(lm, d));
                float s = 0.f, t = 0.f;
#pragma unroll
                for (int ni = 0; ni < 4; ++ni) {
                    const float e = __expf(l[ni] - lm);
                    s += e; t += l[ni] * e;
                }
                float bv = l[0] + gv[0];
                int   bi = vbase;
#pragma unroll
                for (int ni = 1; ni < 4; ++ni) {
                    const float p = l[ni] + gv[ni];
                    const int ci = vbase + ni * 16;
                    if (p > bv) { bv = p; bi = ci; }
                }
#pragma unroll
                for (int d = 1; d < 16; d <<= 1) {
                    s += __shfl_xor(s, d);
                    t += __shfl_xor(t, d);
                    const float ob = __shfl_xor(bv, d);
                    const int   oi = __shfl_xor(bi, d);
                    if (ob > bv || (ob == bv && oi < bi)) { bv = ob; bi = oi; }
                }
                if (fr == 0) {
                    float* pp = part + ((size_t)grow * 64 + grp) * 8;
                    pp[0] = lm; pp[1] = s; pp[2] = t; pp[3] = bv;
                    *(int*)(pp + 4) = bi;
                }
            }
        }
    }
}

// ---------------------------------------------------------------------------
// per-row: merge 64 softmax partials -> entropy/argmax/one-hot/sl; then fused
// LSTM pointwise for the NEXT step (gates = G + E2G[amax]) + embeds output.
template <bool LAST>
__global__ __launch_bounds__(256)
void step_merge(const float* __restrict__ part, const float* __restrict__ G,
                const float* __restrict__ e2g, const float* __restrict__ embedding,
                u16* __restrict__ h_hi, u16* __restrict__ h_lo,
                float* __restrict__ c, float* __restrict__ out,
                int* __restrict__ sl, float* __restrict__ ents, int step)
{
    const int b = blockIdx.x, tid = threadIdx.x;
    __shared__ float sM, sS, sT;
    __shared__ int   sAmax;
    if (tid < 64) {
        const float* pp = part + ((size_t)b * 64 + tid) * 8;
        float m = pp[0], s = pp[1], t = pp[2], bv = pp[3];
        int bi = *(const int*)(pp + 4);
#pragma unroll
        for (int d = 1; d < 64; d <<= 1) {
            const float om = __shfl_xor(m, d), os = __shfl_xor(s, d), ot = __shfl_xor(t, d);
            const float ob = __shfl_xor(bv, d);
            const int   oi = __shfl_xor(bi, d);
            const float M = fmaxf(m, om);
            const float e0 = __expf(m - M), e1 = __expf(om - M);
            s = s * e0 + os * e1;
            t = t * e0 + ot * e1;
            m = M;
            if (ob > bv || (ob == bv && oi < bi)) { bv = ob; bi = oi; }
        }
        if (tid == 0) { sM = m; sS = s; sT = t; sAmax = bi; }
    }
    __syncthreads();
    const int amax = sAmax;

    // zero + one-hot output row (step+1)
    float* orow = out + ((size_t)b * (L_ + 1) + step + 1) * V_;
    const float4 z4 = make_float4(0.f, 0.f, 0.f, 0.f);
    for (int q = tid; q < V_ / 4; q += 256) ((float4*)orow)[q] = z4;
    __syncthreads();
    if (tid == 0) {
        orow[amax] = 1.0f;
        ents[b] += (sM + logf(sS)) - sT / sS;
        if (amax == EOS_ && sl[b] == INIT_LEN_) sl[b] = step + 2;
    }

    if (!LAST) {
        const float* Gr = G + (size_t)b * H4_;
        const float* er = e2g + (size_t)amax * H4_;
#pragma unroll
        for (int jj = 0; jj < 2; ++jj) {
            const int j = tid + jj * 256;
            const float ig = Gr[j]          + er[j];
            const float fg = Gr[H_ + j]     + er[H_ + j];
            const float gg = Gr[2 * H_ + j] + er[2 * H_ + j];
            const float og = Gr[3 * H_ + j] + er[3 * H_ + j];
            const float si = 1.f / (1.f + expf(-ig));
            const float sf = 1.f / (1.f + expf(-fg));
            const float so = 1.f / (1.f + expf(-og));
            const size_t idx = (size_t)b * H_ + j;
            const float cn = sf * c[idx] + si * tanhf(gg);
            c[idx] = cn;
            const float hv = so * tanhf(cn);
            const u16 hh = f2bf(hv);
            h_hi[idx] = hh;
            h_lo[idx] = f2bf(hv - bf2f(hh));
        }
        if (tid < E_)
            out[OUT_EMB + ((size_t)b * L_ + step + 1) * E_ + tid] =
                embedding[(size_t)amax * E_ + tid];
    }
}

// ---------------------------------------------------------------------------
// W_out [H,V] -> transposed hi/lo bf16 splits appended at combined rows
__global__ __launch_bounds__(256)
void split_wout(const float* __restrict__ W_out, u16* __restrict__ hiT,
                u16* __restrict__ loT)
{
    __shared__ float t[32][33];
    const int v0 = blockIdx.x * 32, k0 = blockIdx.y * 32;
    const int x = threadIdx.x & 31, y = threadIdx.x >> 5;
    for (int yy = y; yy < 32; yy += 8)
        t[yy][x] = W_out[(size_t)(k0 + yy) * V_ + v0 + x];
    __syncthreads();
    for (int yy = y; yy < 32; yy += 8) {
        const float v = t[x][yy];
        const u16 h = f2bf(v);
        hiT[(size_t)(v0 + yy) * H_ + k0 + x] = h;
        loT[(size_t)(v0 + yy) * H_ + k0 + x] = f2bf(v - bf2f(h));
    }
}

// elementwise f32 -> bf16 hi/lo split
__global__ __launch_bounds__(256)
void split_mat(const float* __restrict__ X, u16* __restrict__ hi,
               u16* __restrict__ lo)
{
    const int i = blockIdx.x * 256 + threadIdx.x;
    float4 v = ((const float4*)X)[i];
    const u16 h0 = f2bf(v.x), h1 = f2bf(v.y), h2 = f2bf(v.z), h3 = f2bf(v.w);
    ((ushort4*)hi)[i] = make_ushort4(h0, h1, h2, h3);
    ((ushort4*)lo)[i] = make_ushort4(f2bf(v.x - bf2f(h0)), f2bf(v.y - bf2f(h1)),
                                     f2bf(v.z - bf2f(h2)), f2bf(v.w - bf2f(h3)));
}

// h0 = hidden_state @ W_in + b_in (split); c0 = 0
__global__ __launch_bounds__(256)
void h0_kernel(const float* __restrict__ hs, const float* __restrict__ W_in,
               const float* __restrict__ b_in, u16* __restrict__ h_hi,
               u16* __restrict__ h_lo, float* __restrict__ c)
{
    const int idx = blockIdx.x * 256 + threadIdx.x;
    const int b = idx >> 9, j = idx & 511;
    float acc = b_in[j];
#pragma unroll
    for (int e = 0; e < META_; ++e)
        acc = fmaf(hs[b * META_ + e], W_in[e * H_ + j], acc);
    const u16 hh = f2bf(acc);
    h_hi[idx] = hh;
    h_lo[idx] = f2bf(acc - bf2f(hh));
    c[idx] = 0.f;
}

__global__ __launch_bounds__(256)
void init_outputs(float* __restrict__ out, int* __restrict__ tok,
                  int* __restrict__ sl, float* __restrict__ ents)
{
    const int tid = blockIdx.x * 256 + threadIdx.x;
    {
        const int b = tid >> 10;
        const int q = tid & 1023;
        float4 z = make_float4(0.f, 0.f, 0.f, 0.f);
        if (q == 0) z.x = 1.0f;           // SOS = 0
        ((float4*)out)[(size_t)b * ((L_ + 1) * V_ / 4) + q] = z;
    }
    for (size_t t = tid; t < (size_t)B_ * V_; t += (size_t)gridDim.x * 256)
        out[OUT_SP + t] = 0.f;
    if (tid < B_) { tok[tid] = 0; sl[tid] = INIT_LEN_; ents[tid] = 0.f; }
}

// LSTM pointwise for the PRE-LOOP step only (tok=0): gates = G + E2G[tok]
__global__ __launch_bounds__(256)
void lstm_cell(const float* __restrict__ G, const float* __restrict__ e2g,
               u16* __restrict__ h_hi, u16* __restrict__ h_lo,
               float* __restrict__ c, const float* __restrict__ embedding,
               const int* __restrict__ tok, float* __restrict__ out, int step)
{
    const int idx = blockIdx.x * 256 + threadIdx.x;   // B*H
    const int b = idx >> 9, j = idx & 511;
    const size_t g0 = (size_t)b * H4_;
    const size_t e0 = (size_t)tok[b] * H4_;
    const float ig = G[g0 + j]          + e2g[e0 + j];
    const float fg = G[g0 + H_ + j]     + e2g[e0 + H_ + j];
    const float gg = G[g0 + 2 * H_ + j] + e2g[e0 + 2 * H_ + j];
    const float og = G[g0 + 3 * H_ + j] + e2g[e0 + 3 * H_ + j];
    const float si = 1.f / (1.f + expf(-ig));
    const float sf = 1.f / (1.f + expf(-fg));
    const float so = 1.f / (1.f + expf(-og));
    const float cn = sf * c[idx] + si * tanhf(gg);
    c[idx] = cn;
    const float hv = so * tanhf(cn);
    const u16 hh = f2bf(hv);
    h_hi[idx] = hh;
    h_lo[idx] = f2bf(hv - bf2f(hh));
    if (j < E_)
        out[OUT_EMB + ((size_t)b * L_ + step) * E_ + j] =
            embedding[(size_t)tok[b] * E_ + j];
}

__global__ __launch_bounds__(256)
void finalize(const int* __restrict__ sl, const float* __restrict__ ents,
              float* __restrict__ out)
{
    const int tid = threadIdx.x;
    float s = 0.f;
    for (int b = tid; b < B_; b += 256) {
        s += ents[b];
        out[OUT_SL + b] = (float)sl[b];
    }
    __shared__ float red[4];
#pragma unroll
    for (int off = 32; off > 0; off >>= 1) s += __shfl_down(s, off);
    if ((tid & 63) == 0) red[tid >> 6] = s;
    __syncthreads();
    if (tid == 0)
        out[OUT_ENT] = (red[0] + red[1] + red[2] + red[3]) / (float)B_ / (float)L_;
}

// ---------------------------------------------------------------------------
extern "C" void kernel_launch(void* const* d_in, const int* in_sizes, int n_in,
                              void* d_out, int out_size, void* d_ws, size_t ws_size,
                              hipStream_t stream)
{
    const float* hidden    = (const float*)d_in[0];
    const float* W_in      = (const float*)d_in[1];
    const float* b_in      = (const float*)d_in[2];
    const float* embedding = (const float*)d_in[3];
    const float* W_ih      = (const float*)d_in[4];
    const float* W_hh      = (const float*)d_in[5];
    const float* b_ih      = (const float*)d_in[6];
    const float* b_hh      = (const float*)d_in[7];
    const float* W_out     = (const float*)d_in[8];
    const float* b_out     = (const float*)d_in[9];
    const float* gumbel    = (const float*)d_in[10];
    float* out = (float*)d_out;

    float* ws    = (float*)d_ws;
    float* E2G   = ws + WS_E2G;
    float* scr   = ws + WS_SCR;      // partials live here during the loop
    float* G     = ws + WS_G;
    float* c     = ws + WS_C;
    u16*   wsu   = (u16*)(ws + WS_F32_END);
    u16* w6_hi   = wsu + U_W6_HI;
    u16* w6_lo   = wsu + U_W6_LO;
    u16* h_hi    = wsu + U_HHI;
    u16* h_lo    = wsu + U_HLO;
    int* tok     = (int*)(wsu + U_END);
    int* sl      = tok + B_;
    float* ents  = (float*)(sl + B_);
    // emb/wih bf16 splits overlay the scratch region (dead after E2G build)
    u16* emb_hi  = (u16*)scr;
    u16* emb_lo  = emb_hi + (size_t)V_ * E_;
    u16* wih_hi  = emb_lo + (size_t)V_ * E_;
    u16* wih_lo  = wih_hi + (size_t)H4_ * E_;
    float* part  = scr;              // partials: [B][64][8] f32 = 4 MB

    // ---- one-time per call ----
    split_mat<<<(H4_ * H_ / 4) / 256, 256, 0, stream>>>(W_hh, w6_hi, w6_lo);
    split_wout<<<dim3(V_ / 32, H_ / 32), 256, 0, stream>>>(
        W_out, w6_hi + (size_t)H4_ * H_, w6_lo + (size_t)H4_ * H_);
    split_mat<<<(V_ * E_ / 4) / 256, 256, 0, stream>>>(embedding, emb_hi, emb_lo);
    split_mat<<<(H4_ * E_ / 4) / 256, 256, 0, stream>>>(W_ih, wih_hi, wih_lo);
    h0_kernel<<<(B_ * H_) / 256, 256, 0, stream>>>(hidden, W_in, b_in, h_hi, h_lo, c);
    init_outputs<<<(B_ * V_ / 4) / 256, 256, 0, stream>>>(out, tok, sl, ents);
    // E2G = embedding @ W_ih^T + b_ih + b_hh   [V, 4H]
    gemm3<0><<<dim3(H4_ / 128, V_ / 128), 256, 0, stream>>>(
        emb_hi, emb_lo, wih_hi, wih_lo, E2G, nullptr, E_, b_ih, b_hh,
        nullptr, 0, 0);
    // G0 = h0 @ W_hh^T (gates panels only)
    gemm3<1><<<dim3(H4_ / 128, B_ / 128), 256, 0, stream>>>(
        h_hi, h_lo, w6_hi, w6_lo, G, part, H_, b_out, nullptr, gumbel, 0, 0);
    // pointwise step 0 (tok=0) -> h1, embeds row 0
    lstm_cell<<<(B_ * H_) / 256, 256, 0, stream>>>(G, E2G, h_hi, h_lo, c,
                                                   embedding, tok, out, 0);

    for (int i = 0; i < L_; ++i) {
        if (i < L_ - 1) {
            // [G_{i+1} | partials(logits_i)] = h_{i+1} @ [W_hh | WoutT]^T
            gemm3<1><<<dim3(W6_ / 128, B_ / 128), 256, 0, stream>>>(
                h_hi, h_lo, w6_hi, w6_lo, G, part, H_, b_out, nullptr,
                gumbel, i, 0);
            step_merge<false><<<B_, 256, 0, stream>>>(
                part, G, E2G, embedding, h_hi, h_lo, c, out, sl, ents, i);
        } else {
            // logits partials only
            gemm3<1><<<dim3(V_ / 128, B_ / 128), 256, 0, stream>>>(
                h_hi, h_lo, w6_hi, w6_lo, G, part, H_, b_out, nullptr,
                gumbel, i, H4_ / 128);
            step_merge<true><<<B_, 256, 0, stream>>>(
                part, G, E2G, embedding, h_hi, h_lo, c, out, sl, ents, i);
        }
    }
    finalize<<<1, 256, 0, stream>>>(sl, ents, out);
}

// Round 8
// 835.207 us; speedup vs baseline: 1.3153x; 1.2633x over previous
//
#include <hip/hip_runtime.h>
#include <hip/hip_bf16.h>
#include <math.h>

typedef unsigned short u16;
typedef __attribute__((ext_vector_type(8))) short bf16x8;
typedef __attribute__((ext_vector_type(4))) float f32x4;

#define B_    2048
#define V_    4096
#define L_    10
#define H_    512
#define E_    256
#define META_ 15
#define H4_   2048
#define W6_   (H4_ + V_)          // 6144 combined B rows (W_hh | WoutT)
#define EOS_  0
#define INIT_LEN_ (L_ + 1)

// ---- output layout (flat float32, reference return order) ----
constexpr size_t OUT_SL  = (size_t)B_ * (L_ + 1) * V_;
constexpr size_t OUT_ENT = OUT_SL + B_;
constexpr size_t OUT_EMB = OUT_ENT + 1;
constexpr size_t OUT_SP  = OUT_EMB + (size_t)B_ * L_ * E_;

// ---- workspace layout ----
// f32: E2G [V,4H] | LOGITS [B,V] | G [B,4H] | c [B,H]
// u16: w6_hi/lo [6144,512] | h_hi/lo [B,H]
constexpr size_t WS_E2G     = 0;
constexpr size_t WS_LOGITS  = WS_E2G    + (size_t)V_ * H4_;
constexpr size_t WS_G       = WS_LOGITS + (size_t)B_ * V_;
constexpr size_t WS_C       = WS_G      + (size_t)B_ * H4_;
constexpr size_t WS_F32_END = WS_C      + (size_t)B_ * H_;
constexpr size_t U_W6_HI    = 0;
constexpr size_t U_W6_LO    = U_W6_HI + (size_t)W6_ * H_;
constexpr size_t U_HHI      = U_W6_LO + (size_t)W6_ * H_;
constexpr size_t U_HLO      = U_HHI   + (size_t)B_ * H_;
constexpr size_t U_END      = U_HLO   + (size_t)B_ * H_;

__device__ __forceinline__ u16 f2bf(float f) {
    union { __hip_bfloat16 b; u16 u; } cv; cv.b = __float2bfloat16(f); return cv.u;
}
__device__ __forceinline__ float bf2f(u16 u) {
    union { u16 u; __hip_bfloat16 b; } cv; cv.u = u; return __bfloat162float(cv.b);
}

__device__ __forceinline__ void gld16(const u16* g, void* l) {
    __builtin_amdgcn_global_load_lds(
        (const __attribute__((address_space(1))) unsigned int*)g,
        (__attribute__((address_space(3))) unsigned int*)l, 16, 0, 0);
}

// ---------------------------------------------------------------------------
// bf16x3 split MFMA NT GEMM (round-3 structure, unchanged).
// 128x128 tile, BK=32, 4 waves 2x2.
// EPI 0: C0[row,col] (ldc=4H) += bias0[col] + bias1[col]       (E2G build)
// EPI 1: col<4H -> C0=G (ldc=4H, raw); col>=4H -> C1=LOGITS (ldc=V) + bias0
// ---------------------------------------------------------------------------
template <int EPI>
__global__ __launch_bounds__(256)
void gemm3(const u16* __restrict__ Ah, const u16* __restrict__ Al,
           const u16* __restrict__ Bh, const u16* __restrict__ Bl,
           float* __restrict__ C0, float* __restrict__ C1, int K,
           const float* __restrict__ bias0, const float* __restrict__ bias1,
           int xoff)
{
    __shared__ u16 As[2][128][32];
    __shared__ u16 Bs[2][128][32];
    const int tid  = threadIdx.x;
    const int lane = tid & 63;
    const int wave = tid >> 6;
    const int wm = wave >> 1, wn = wave & 1;

    // bijective XCD-chunked swizzle, column-clustered
    const int nwg  = gridDim.x * gridDim.y;
    const int bid  = blockIdx.y * gridDim.x + blockIdx.x;
    const int w    = (bid & 7) * (nwg >> 3) + (bid >> 3);
    const int colb = w / gridDim.y + xoff;
    const int rowb = w % gridDim.y;
    const int col0 = colb * 128;
    const int row0 = rowb * 128;

    const int srow = tid >> 2;
    const int scol = (tid & 3) * 8;
    const size_t aoff = (size_t)(row0 + srow) * K + scol;
    const size_t boff = (size_t)(col0 + srow) * K + scol;
    const size_t skip = (size_t)64 * K;

    u16* lA0 = &As[0][0][0];
    u16* lA1 = &As[1][0][0];
    u16* lB0 = &Bs[0][0][0];
    u16* lB1 = &Bs[1][0][0];
    const int d0 = tid * 8;
    const int d1 = d0 + 2048;

    f32x4 acc[4][4] = {};
    const int fr = lane & 15;
    const int kq = lane >> 4;

    for (int k0 = 0; k0 < K; k0 += 32) {
        __syncthreads();
        gld16(Ah + aoff + k0,        lA0 + d0);
        gld16(Ah + aoff + k0 + skip, lA0 + d1);
        gld16(Al + aoff + k0,        lA1 + d0);
        gld16(Al + aoff + k0 + skip, lA1 + d1);
        gld16(Bh + boff + k0,        lB0 + d0);
        gld16(Bh + boff + k0 + skip, lB0 + d1);
        gld16(Bl + boff + k0,        lB1 + d0);
        gld16(Bl + boff + k0 + skip, lB1 + d1);
        __syncthreads();

        bf16x8 ah[4], al[4], bh[4], bl[4];
#pragma unroll
        for (int i = 0; i < 4; ++i) {
            ah[i] = *(const bf16x8*)&As[0][wm * 64 + i * 16 + fr][kq * 8];
            al[i] = *(const bf16x8*)&As[1][wm * 64 + i * 16 + fr][kq * 8];
            bh[i] = *(const bf16x8*)&Bs[0][wn * 64 + i * 16 + fr][kq * 8];
            bl[i] = *(const bf16x8*)&Bs[1][wn * 64 + i * 16 + fr][kq * 8];
        }
#pragma unroll
        for (int mi = 0; mi < 4; ++mi)
#pragma unroll
            for (int ni = 0; ni < 4; ++ni) {
                acc[mi][ni] = __builtin_amdgcn_mfma_f32_16x16x32_bf16(ah[mi], bh[ni], acc[mi][ni], 0, 0, 0);
                acc[mi][ni] = __builtin_amdgcn_mfma_f32_16x16x32_bf16(ah[mi], bl[ni], acc[mi][ni], 0, 0, 0);
                acc[mi][ni] = __builtin_amdgcn_mfma_f32_16x16x32_bf16(al[mi], bh[ni], acc[mi][ni], 0, 0, 0);
            }
    }

    // C/D layout: col = lane&15, row = (lane>>4)*4 + reg
    const int cc0 = col0 + wn * 64 + fr;
    float* Cbase;
    int ldc, ccol;
    bool addBias;
    if (EPI == 0) {
        Cbase = C0; ldc = H4_; ccol = cc0; addBias = true;
    } else {
        const bool isG = (col0 < H4_);
        Cbase = isG ? C0 : C1;
        ldc   = isG ? H4_ : V_;
        ccol  = isG ? cc0 : cc0 - H4_;
        addBias = !isG;
    }
#pragma unroll
    for (int mi = 0; mi < 4; ++mi) {
#pragma unroll
        for (int r = 0; r < 4; ++r) {
            const int grow = row0 + wm * 64 + mi * 16 + kq * 4 + r;
            float* cp = Cbase + (size_t)grow * ldc + ccol;
#pragma unroll
            for (int ni = 0; ni < 4; ++ni) {
                float v = acc[mi][ni][r];
                if (EPI == 0) v += bias0[ccol + ni * 16] + bias1[ccol + ni * 16];
                if (EPI == 1 && addBias) v += bias0[ccol + ni * 16];
                cp[ni * 16] = v;
            }
        }
    }
}

// ---------------------------------------------------------------------------
// per-row: softmax (entropy/LSE) + argmax(logits+gumbel) + one-hot write +
// sl/ents update, then fused LSTM pointwise for the NEXT step
// (gates = G + E2G[amax]) + embeds row step+1.
template <bool LAST>
__global__ __launch_bounds__(256)
void step_merge(const float* __restrict__ logits, const float* __restrict__ gumbel,
                const float* __restrict__ G, const float* __restrict__ e2g,
                const float* __restrict__ embedding,
                u16* __restrict__ h_hi, u16* __restrict__ h_lo,
                float* __restrict__ c, float* __restrict__ out,
                int* __restrict__ sl, float* __restrict__ ents, int step)
{
    const int b   = blockIdx.x;
    const int tid = threadIdx.x;
    const float* lrow = logits + (size_t)b * V_;
    const float* grow = gumbel + ((size_t)step * B_ + b) * V_;
    __shared__ float lsm[V_];
    __shared__ float red_m[4], red_bv[4], red_s[4], red_t[4];
    __shared__ int   red_bi[4];
    __shared__ float s_M;
    __shared__ int   s_bi;

    float m = -3.4e38f, bv = -3.4e38f;
    int bi = 0x7fffffff;
    for (int q = tid; q < V_ / 4; q += 256) {
        float4 l4 = ((const float4*)lrow)[q];
        float4 g4 = ((const float4*)grow)[q];
        ((float4*)lsm)[q] = l4;
        m = fmaxf(m, fmaxf(fmaxf(l4.x, l4.y), fmaxf(l4.z, l4.w)));
        float p; const int i4 = q * 4;
        p = l4.x + g4.x; if (p > bv) { bv = p; bi = i4; }
        p = l4.y + g4.y; if (p > bv) { bv = p; bi = i4 + 1; }
        p = l4.z + g4.z; if (p > bv) { bv = p; bi = i4 + 2; }
        p = l4.w + g4.w; if (p > bv) { bv = p; bi = i4 + 3; }
    }
#pragma unroll
    for (int off = 32; off > 0; off >>= 1) {
        m = fmaxf(m, __shfl_down(m, off));
        float obv = __shfl_down(bv, off);
        int   obi = __shfl_down(bi, off);
        if (obv > bv || (obv == bv && obi < bi)) { bv = obv; bi = obi; }
    }
    const int wave = tid >> 6, lane = tid & 63;
    if (lane == 0) { red_m[wave] = m; red_bv[wave] = bv; red_bi[wave] = bi; }
    __syncthreads();
    if (tid == 0) {
        m = red_m[0]; bv = red_bv[0]; bi = red_bi[0];
        for (int w = 1; w < 4; ++w) {
            m = fmaxf(m, red_m[w]);
            if (red_bv[w] > bv || (red_bv[w] == bv && red_bi[w] < bi)) {
                bv = red_bv[w]; bi = red_bi[w];
            }
        }
        s_M = m; s_bi = bi;
    }
    __syncthreads();
    const float M = s_M;
    const int amax = s_bi;

    float s = 0.f, t = 0.f;
    for (int q = tid; q < V_; q += 256) {
        const float l = lsm[q];
        const float e = __expf(l - M);
        s += e; t += e * l;
    }
#pragma unroll
    for (int off = 32; off > 0; off >>= 1) {
        s += __shfl_down(s, off);
        t += __shfl_down(t, off);
    }
    if (lane == 0) { red_s[wave] = s; red_t[wave] = t; }

    // zero + one-hot output row (step+1)
    float* orow = out + ((size_t)b * (L_ + 1) + step + 1) * V_;
    const float4 z4 = make_float4(0.f, 0.f, 0.f, 0.f);
    for (int q = tid; q < V_ / 4; q += 256) ((float4*)orow)[q] = z4;
    __syncthreads();
    if (tid == 0) {
        const float ss = red_s[0] + red_s[1] + red_s[2] + red_s[3];
        const float tt = red_t[0] + red_t[1] + red_t[2] + red_t[3];
        ents[b] += (M + logf(ss)) - tt / ss;
        orow[amax] = 1.0f;
        if (amax == EOS_ && sl[b] == INIT_LEN_) sl[b] = step + 2;
    }

    if (!LAST) {
        const float* Gr = G + (size_t)b * H4_;
        const float* er = e2g + (size_t)amax * H4_;
#pragma unroll
        for (int jj = 0; jj < 2; ++jj) {
            const int j = tid + jj * 256;
            const float ig = Gr[j]          + er[j];
            const float fg = Gr[H_ + j]     + er[H_ + j];
            const float gg = Gr[2 * H_ + j] + er[2 * H_ + j];
            const float og = Gr[3 * H_ + j] + er[3 * H_ + j];
            const float si = 1.f / (1.f + expf(-ig));
            const float sf = 1.f / (1.f + expf(-fg));
            const float so = 1.f / (1.f + expf(-og));
            const size_t idx = (size_t)b * H_ + j;
            const float cn = sf * c[idx] + si * tanhf(gg);
            c[idx] = cn;
            const float hv = so * tanhf(cn);
            const u16 hh = f2bf(hv);
            h_hi[idx] = hh;
            h_lo[idx] = f2bf(hv - bf2f(hh));
        }
        if (tid < E_)
            out[OUT_EMB + ((size_t)b * L_ + step + 1) * E_ + tid] =
                embedding[(size_t)amax * E_ + tid];
    }
}

// ---------------------------------------------------------------------------
// W_out [H,V] -> transposed hi/lo bf16 splits appended at combined rows
__global__ __launch_bounds__(256)
void split_wout(const float* __restrict__ W_out, u16* __restrict__ hiT,
                u16* __restrict__ loT)
{
    __shared__ float t[32][33];
    const int v0 = blockIdx.x * 32, k0 = blockIdx.y * 32;
    const int x = threadIdx.x & 31, y = threadIdx.x >> 5;
    for (int yy = y; yy < 32; yy += 8)
        t[yy][x] = W_out[(size_t)(k0 + yy) * V_ + v0 + x];
    __syncthreads();
    for (int yy = y; yy < 32; yy += 8) {
        const float v = t[x][yy];
        const u16 h = f2bf(v);
        hiT[(size_t)(v0 + yy) * H_ + k0 + x] = h;
        loT[(size_t)(v0 + yy) * H_ + k0 + x] = f2bf(v - bf2f(h));
    }
}

// elementwise f32 -> bf16 hi/lo split
__global__ __launch_bounds__(256)
void split_mat(const float* __restrict__ X, u16* __restrict__ hi,
               u16* __restrict__ lo)
{
    const int i = blockIdx.x * 256 + threadIdx.x;
    float4 v = ((const float4*)X)[i];
    const u16 h0 = f2bf(v.x), h1 = f2bf(v.y), h2 = f2bf(v.z), h3 = f2bf(v.w);
    ((ushort4*)hi)[i] = make_ushort4(h0, h1, h2, h3);
    ((ushort4*)lo)[i] = make_ushort4(f2bf(v.x - bf2f(h0)), f2bf(v.y - bf2f(h1)),
                                     f2bf(v.z - bf2f(h2)), f2bf(v.w - bf2f(h3)));
}

// h0 = hidden_state @ W_in + b_in (split); c0 = 0
__global__ __launch_bounds__(256)
void h0_kernel(const float* __restrict__ hs, const float* __restrict__ W_in,
               const float* __restrict__ b_in, u16* __restrict__ h_hi,
               u16* __restrict__ h_lo, float* __restrict__ c)
{
    const int idx = blockIdx.x * 256 + threadIdx.x;
    const int b = idx >> 9, j = idx & 511;
    float acc = b_in[j];
#pragma unroll
    for (int e = 0; e < META_; ++e)
        acc = fmaf(hs[b * META_ + e], W_in[e * H_ + j], acc);
    const u16 hh = f2bf(acc);
    h_hi[idx] = hh;
    h_lo[idx] = f2bf(acc - bf2f(hh));
    c[idx] = 0.f;
}

__global__ __launch_bounds__(256)
void init_outputs(float* __restrict__ out, int* __restrict__ tok,
                  int* __restrict__ sl, float* __restrict__ ents)
{
    const int tid = blockIdx.x * 256 + threadIdx.x;
    {
        const int b = tid >> 10;
        const int q = tid & 1023;
        float4 z = make_float4(0.f, 0.f, 0.f, 0.f);
        if (q == 0) z.x = 1.0f;           // SOS = 0
        ((float4*)out)[(size_t)b * ((L_ + 1) * V_ / 4) + q] = z;
    }
    for (size_t t = tid; t < (size_t)B_ * V_; t += (size_t)gridDim.x * 256)
        out[OUT_SP + t] = 0.f;
    if (tid < B_) { tok[tid] = 0; sl[tid] = INIT_LEN_; ents[tid] = 0.f; }
}

// LSTM pointwise for the PRE-LOOP step only (tok=0): gates = G + E2G[tok]
__global__ __launch_bounds__(256)
void lstm_cell(const float* __restrict__ G, const float* __restrict__ e2g,
               u16* __restrict__ h_hi, u16* __restrict__ h_lo,
               float* __restrict__ c, const float* __restrict__ embedding,
               const int* __restrict__ tok, float* __restrict__ out, int step)
{
    const int idx = blockIdx.x * 256 + threadIdx.x;   // B*H
    const int b = idx >> 9, j = idx & 511;
    const size_t g0 = (size_t)b * H4_;
    const size_t e0 = (size_t)tok[b] * H4_;
    const float ig = G[g0 + j]          + e2g[e0 + j];
    const float fg = G[g0 + H_ + j]     + e2g[e0 + H_ + j];
    const float gg = G[g0 + 2 * H_ + j] + e2g[e0 + 2 * H_ + j];
    const float og = G[g0 + 3 * H_ + j] + e2g[e0 + 3 * H_ + j];
    const float si = 1.f / (1.f + expf(-ig));
    const float sf = 1.f / (1.f + expf(-fg));
    const float so = 1.f / (1.f + expf(-og));
    const float cn = sf * c[idx] + si * tanhf(gg);
    c[idx] = cn;
    const float hv = so * tanhf(cn);
    const u16 hh = f2bf(hv);
    h_hi[idx] = hh;
    h_lo[idx] = f2bf(hv - bf2f(hh));
    if (j < E_)
        out[OUT_EMB + ((size_t)b * L_ + step) * E_ + j] =
            embedding[(size_t)tok[b] * E_ + j];
}

__global__ __launch_bounds__(256)
void finalize(const int* __restrict__ sl, const float* __restrict__ ents,
              float* __restrict__ out)
{
    const int tid = threadIdx.x;
    float s = 0.f;
    for (int b = tid; b < B_; b += 256) {
        s += ents[b];
        out[OUT_SL + b] = (float)sl[b];
    }
    __shared__ float red[4];
#pragma unroll
    for (int off = 32; off > 0; off >>= 1) s += __shfl_down(s, off);
    if ((tid & 63) == 0) red[tid >> 6] = s;
    __syncthreads();
    if (tid == 0)
        out[OUT_ENT] = (red[0] + red[1] + red[2] + red[3]) / (float)B_ / (float)L_;
}

// ---------------------------------------------------------------------------
extern "C" void kernel_launch(void* const* d_in, const int* in_sizes, int n_in,
                              void* d_out, int out_size, void* d_ws, size_t ws_size,
                              hipStream_t stream)
{
    const float* hidden    = (const float*)d_in[0];
    const float* W_in      = (const float*)d_in[1];
    const float* b_in      = (const float*)d_in[2];
    const float* embedding = (const float*)d_in[3];
    const float* W_ih      = (const float*)d_in[4];
    const float* W_hh      = (const float*)d_in[5];
    const float* b_ih      = (const float*)d_in[6];
    const float* b_hh      = (const float*)d_in[7];
    const float* W_out     = (const float*)d_in[8];
    const float* b_out     = (const float*)d_in[9];
    const float* gumbel    = (const float*)d_in[10];
    float* out = (float*)d_out;

    float* ws    = (float*)d_ws;
    float* E2G   = ws + WS_E2G;
    float* logit = ws + WS_LOGITS;
    float* G     = ws + WS_G;
    float* c     = ws + WS_C;
    u16*   wsu   = (u16*)(ws + WS_F32_END);
    u16* w6_hi   = wsu + U_W6_HI;
    u16* w6_lo   = wsu + U_W6_LO;
    u16* h_hi    = wsu + U_HHI;
    u16* h_lo    = wsu + U_HLO;
    int* tok     = (int*)(wsu + U_END);
    int* sl      = tok + B_;
    float* ents  = (float*)(sl + B_);
    // emb/wih bf16 splits overlay the LOGITS region (dead after E2G build)
    u16* emb_hi  = (u16*)logit;
    u16* emb_lo  = emb_hi + (size_t)V_ * E_;
    u16* wih_hi  = emb_lo + (size_t)V_ * E_;
    u16* wih_lo  = wih_hi + (size_t)H4_ * E_;

    // ---- one-time per call ----
    split_mat<<<(H4_ * H_ / 4) / 256, 256, 0, stream>>>(W_hh, w6_hi, w6_lo);
    split_wout<<<dim3(V_ / 32, H_ / 32), 256, 0, stream>>>(
        W_out, w6_hi + (size_t)H4_ * H_, w6_lo + (size_t)H4_ * H_);
    split_mat<<<(V_ * E_ / 4) / 256, 256, 0, stream>>>(embedding, emb_hi, emb_lo);
    split_mat<<<(H4_ * E_ / 4) / 256, 256, 0, stream>>>(W_ih, wih_hi, wih_lo);
    h0_kernel<<<(B_ * H_) / 256, 256, 0, stream>>>(hidden, W_in, b_in, h_hi, h_lo, c);
    init_outputs<<<(B_ * V_ / 4) / 256, 256, 0, stream>>>(out, tok, sl, ents);
    // E2G = embedding @ W_ih^T + b_ih + b_hh   [V, 4H]
    gemm3<0><<<dim3(H4_ / 128, V_ / 128), 256, 0, stream>>>(
        emb_hi, emb_lo, wih_hi, wih_lo, E2G, nullptr, E_, b_ih, b_hh, 0);
    // G0 = h0 @ W_hh^T (gates panels only)
    gemm3<1><<<dim3(H4_ / 128, B_ / 128), 256, 0, stream>>>(
        h_hi, h_lo, w6_hi, w6_lo, G, logit, H_, b_out, nullptr, 0);
    // pointwise step 0 (tok=0) -> h1, embeds row 0
    lstm_cell<<<(B_ * H_) / 256, 256, 0, stream>>>(G, E2G, h_hi, h_lo, c,
                                                   embedding, tok, out, 0);

    for (int i = 0; i < L_; ++i) {
        if (i < L_ - 1) {
            // [G_{i+1} | logits_i] = h_{i+1} @ [W_hh | WoutT]^T
            gemm3<1><<<dim3(W6_ / 128, B_ / 128), 256, 0, stream>>>(
                h_hi, h_lo, w6_hi, w6_lo, G, logit, H_, b_out, nullptr, 0);
            step_merge<false><<<B_, 256, 0, stream>>>(
                logit, gumbel, G, E2G, embedding, h_hi, h_lo, c, out,
                sl, ents, i);
        } else {
            // logits only
            gemm3<1><<<dim3(V_ / 128, B_ / 128), 256, 0, stream>>>(
                h_hi, h_lo, w6_hi, w6_lo, G, logit, H_, b_out, nullptr,
                H4_ / 128);
            step_merge<true><<<B_, 256, 0, stream>>>(
                logit, gumbel, G, E2G, embedding, h_hi, h_lo, c, out,
                sl, ents, i);
        }
    }
    finalize<<<1, 256, 0, stream>>>(sl, ents, out);
}

// Round 9
// 792.516 us; speedup vs baseline: 1.3862x; 1.0539x over previous
//
#include <hip/hip_runtime.h>
#include <hip/hip_bf16.h>
#include <math.h>

typedef unsigned short u16;
typedef __attribute__((ext_vector_type(8))) short bf16x8;
typedef __attribute__((ext_vector_type(4))) float f32x4;
typedef __attribute__((ext_vector_type(16))) float f32x16;

#define B_    2048
#define V_    4096
#define L_    10
#define H_    512
#define E_    256
#define META_ 15
#define H4_   2048
#define W6_   (H4_ + V_)          // 6144 combined B rows (W_hh | WoutT)
#define EOS_  0
#define INIT_LEN_ (L_ + 1)

// ---- output layout (flat float32, reference return order) ----
constexpr size_t OUT_SL  = (size_t)B_ * (L_ + 1) * V_;
constexpr size_t OUT_ENT = OUT_SL + B_;
constexpr size_t OUT_EMB = OUT_ENT + 1;
constexpr size_t OUT_SP  = OUT_EMB + (size_t)B_ * L_ * E_;

// ---- workspace layout ----
// f32: E2G [V,4H] | LOGITS [B,V] | G [B,4H] | c [B,H]
// u16: Bh_pk/Bl_pk [6144*512] packed | Ah_pk/Al_pk [2048*512] packed
constexpr size_t WS_E2G     = 0;
constexpr size_t WS_LOGITS  = WS_E2G    + (size_t)V_ * H4_;
constexpr size_t WS_G       = WS_LOGITS + (size_t)B_ * V_;
constexpr size_t WS_C       = WS_G      + (size_t)B_ * H4_;
constexpr size_t WS_F32_END = WS_C      + (size_t)B_ * H_;
constexpr size_t U_BH       = 0;
constexpr size_t U_BL       = U_BH + (size_t)W6_ * H_;
constexpr size_t U_AH       = U_BL + (size_t)W6_ * H_;
constexpr size_t U_AL       = U_AH + (size_t)B_ * H_;
constexpr size_t U_END      = U_AL + (size_t)B_ * H_;

__device__ __forceinline__ u16 f2bf(float f) {
    union { __hip_bfloat16 b; u16 u; } cv; cv.b = __float2bfloat16(f); return cv.u;
}
__device__ __forceinline__ float bf2f(u16 u) {
    union { u16 u; __hip_bfloat16 b; } cv; cv.u = u; return __bfloat162float(cv.b);
}
__device__ __forceinline__ void gld16(const u16* g, void* l) {
    __builtin_amdgcn_global_load_lds(
        (const __attribute__((address_space(1))) unsigned int*)g,
        (__attribute__((address_space(3))) unsigned int*)l, 16, 0, 0);
}

// packed addressing (K=512 for both A and B):
// [panel = r>>7][ktile = k>>5][s = (k>>3)&3][row = r&127][e = k&7]
__device__ __forceinline__ size_t a_pk(int r, int k) {
    return (size_t)(r >> 7) * 65536 + (size_t)(k >> 5) * 4096 +
           (size_t)((k >> 3) & 3) * 1024 + (size_t)(r & 127) * 8 + (k & 7);
}

// ---------------------------------------------------------------------------
// bf16x3 split MFMA NT GEMM, 32x32x16 shape, packed operands.
// 128x128 tile, BK=32, 4 waves 2x2, r3's 2-barrier schedule.
// col panels < 16 -> G (ldc=4H, raw); panels >= 16 -> LOGITS (ldc=V) + bias.
// ---------------------------------------------------------------------------
__global__ __launch_bounds__(256)
void gemm32(const u16* __restrict__ Ah, const u16* __restrict__ Al,
            const u16* __restrict__ Bh, const u16* __restrict__ Bl,
            float* __restrict__ C0, float* __restrict__ C1,
            const float* __restrict__ bias0, int xoff)
{
    __shared__ u16 As[2][4096];   // [split][s4][row128][e8]
    __shared__ u16 Bs[2][4096];
    const int tid  = threadIdx.x;
    const int lane = tid & 63;
    const int wave = tid >> 6;
    const int wm = wave >> 1, wn = wave & 1;
    const int l31 = lane & 31, lh = lane >> 5;

    // bijective XCD-chunked swizzle, column-clustered
    const int nwg  = gridDim.x * gridDim.y;
    const int bid  = blockIdx.y * gridDim.x + blockIdx.x;
    const int w    = (bid & 7) * (nwg >> 3) + (bid >> 3);
    const int colb = w / gridDim.y + xoff;
    const int rowb = w % gridDim.y;
    const int col0 = colb * 128;
    const int row0 = rowb * 128;

    const u16* Ah_p = Ah + (size_t)rowb * 65536;
    const u16* Al_p = Al + (size_t)rowb * 65536;
    const u16* Bh_p = Bh + (size_t)colb * 65536;
    const u16* Bl_p = Bl + (size_t)colb * 65536;
    const int d0 = tid * 8;
    const int d1 = d0 + 2048;

    // frag element bases in a 4096-elem tile: + kh*2048 + (rg|cg)*256
    const int abase = lh * 1024 + (wm * 64 + l31) * 8;
    const int bbase = lh * 1024 + (wn * 64 + l31) * 8;

    f32x16 acc[2][2] = {};

    for (int t = 0; t < 16; ++t) {               // K = 512, BK = 32
        const int g0 = t * 4096;
        __syncthreads();
        gld16(Ah_p + g0 + d0, &As[0][d0]);
        gld16(Ah_p + g0 + d1, &As[0][d1]);
        gld16(Al_p + g0 + d0, &As[1][d0]);
        gld16(Al_p + g0 + d1, &As[1][d1]);
        gld16(Bh_p + g0 + d0, &Bs[0][d0]);
        gld16(Bh_p + g0 + d1, &Bs[0][d1]);
        gld16(Bl_p + g0 + d0, &Bs[1][d0]);
        gld16(Bl_p + g0 + d1, &Bs[1][d1]);
        __syncthreads();

        bf16x8 ah[2][2], al[2][2], bh[2][2], bl[2][2];
#pragma unroll
        for (int kh = 0; kh < 2; ++kh)
#pragma unroll
            for (int g = 0; g < 2; ++g) {
                ah[kh][g] = *(const bf16x8*)&As[0][abase + kh * 2048 + g * 256];
                al[kh][g] = *(const bf16x8*)&As[1][abase + kh * 2048 + g * 256];
                bh[kh][g] = *(const bf16x8*)&Bs[0][bbase + kh * 2048 + g * 256];
                bl[kh][g] = *(const bf16x8*)&Bs[1][bbase + kh * 2048 + g * 256];
            }
#pragma unroll
        for (int kh = 0; kh < 2; ++kh)
#pragma unroll
            for (int rg = 0; rg < 2; ++rg)
#pragma unroll
                for (int cg = 0; cg < 2; ++cg) {
                    acc[rg][cg] = __builtin_amdgcn_mfma_f32_32x32x16_bf16(
                        ah[kh][rg], bh[kh][cg], acc[rg][cg], 0, 0, 0);
                    acc[rg][cg] = __builtin_amdgcn_mfma_f32_32x32x16_bf16(
                        ah[kh][rg], bl[kh][cg], acc[rg][cg], 0, 0, 0);
                    acc[rg][cg] = __builtin_amdgcn_mfma_f32_32x32x16_bf16(
                        al[kh][rg], bh[kh][cg], acc[rg][cg], 0, 0, 0);
                }
    }

    // 32x32 C/D layout: col = lane&31, row = (reg&3) + 8*(reg>>2) + 4*(lane>>5)
    const bool isG  = (col0 < H4_);
    float* Cb       = isG ? C0 : C1;
    const int ldc   = isG ? H4_ : V_;
    const int ccol0 = (isG ? col0 : col0 - H4_) + wn * 64 + l31;
    const int rbase = row0 + wm * 64 + 4 * lh;
#pragma unroll
    for (int rg = 0; rg < 2; ++rg)
#pragma unroll
        for (int cg = 0; cg < 2; ++cg) {
            const int ccol = ccol0 + cg * 32;
            const float bv = isG ? 0.f : bias0[ccol];
#pragma unroll
            for (int reg = 0; reg < 16; ++reg) {
                const int row = rbase + rg * 32 + (reg & 3) + 8 * (reg >> 2);
                Cb[(size_t)row * ldc + ccol] = acc[rg][cg][reg] + bv;
            }
        }
}

// ---------------------------------------------------------------------------
// old 16x16 MFMA GEMM kept for the one-time E2G build (row-major splits)
__global__ __launch_bounds__(256)
void gemm_e2g(const u16* __restrict__ Ah, const u16* __restrict__ Al,
              const u16* __restrict__ Bh, const u16* __restrict__ Bl,
              float* __restrict__ C0, int K,
              const float* __restrict__ bias0, const float* __restrict__ bias1)
{
    __shared__ u16 As[2][128][32];
    __shared__ u16 Bs[2][128][32];
    const int tid  = threadIdx.x;
    const int lane = tid & 63;
    const int wave = tid >> 6;
    const int wm = wave >> 1, wn = wave & 1;
    const int nwg  = gridDim.x * gridDim.y;
    const int bid  = blockIdx.y * gridDim.x + blockIdx.x;
    const int w    = (bid & 7) * (nwg >> 3) + (bid >> 3);
    const int colb = w / gridDim.y;
    const int rowb = w % gridDim.y;
    const int col0 = colb * 128;
    const int row0 = rowb * 128;

    const int srow = tid >> 2;
    const int scol = (tid & 3) * 8;
    const size_t aoff = (size_t)(row0 + srow) * K + scol;
    const size_t boff = (size_t)(col0 + srow) * K + scol;
    const size_t skip = (size_t)64 * K;

    u16* lA0 = &As[0][0][0];
    u16* lA1 = &As[1][0][0];
    u16* lB0 = &Bs[0][0][0];
    u16* lB1 = &Bs[1][0][0];
    const int d0 = tid * 8;
    const int d1 = d0 + 2048;

    f32x4 acc[4][4] = {};
    const int fr = lane & 15;
    const int kq = lane >> 4;

    for (int k0 = 0; k0 < K; k0 += 32) {
        __syncthreads();
        gld16(Ah + aoff + k0,        lA0 + d0);
        gld16(Ah + aoff + k0 + skip, lA0 + d1);
        gld16(Al + aoff + k0,        lA1 + d0);
        gld16(Al + aoff + k0 + skip, lA1 + d1);
        gld16(Bh + boff + k0,        lB0 + d0);
        gld16(Bh + boff + k0 + skip, lB0 + d1);
        gld16(Bl + boff + k0,        lB1 + d0);
        gld16(Bl + boff + k0 + skip, lB1 + d1);
        __syncthreads();

        bf16x8 ah[4], al[4], bh[4], bl[4];
#pragma unroll
        for (int i = 0; i < 4; ++i) {
            ah[i] = *(const bf16x8*)&As[0][wm * 64 + i * 16 + fr][kq * 8];
            al[i] = *(const bf16x8*)&As[1][wm * 64 + i * 16 + fr][kq * 8];
            bh[i] = *(const bf16x8*)&Bs[0][wn * 64 + i * 16 + fr][kq * 8];
            bl[i] = *(const bf16x8*)&Bs[1][wn * 64 + i * 16 + fr][kq * 8];
        }
#pragma unroll
        for (int mi = 0; mi < 4; ++mi)
#pragma unroll
            for (int ni = 0; ni < 4; ++ni) {
                acc[mi][ni] = __builtin_amdgcn_mfma_f32_16x16x32_bf16(ah[mi], bh[ni], acc[mi][ni], 0, 0, 0);
                acc[mi][ni] = __builtin_amdgcn_mfma_f32_16x16x32_bf16(ah[mi], bl[ni], acc[mi][ni], 0, 0, 0);
                acc[mi][ni] = __builtin_amdgcn_mfma_f32_16x16x32_bf16(al[mi], bh[ni], acc[mi][ni], 0, 0, 0);
            }
    }

    const int cc0 = col0 + wn * 64 + fr;
#pragma unroll
    for (int mi = 0; mi < 4; ++mi) {
#pragma unroll
        for (int r = 0; r < 4; ++r) {
            const int grow = row0 + wm * 64 + mi * 16 + kq * 4 + r;
            float* cp = C0 + (size_t)grow * H4_ + cc0;
#pragma unroll
            for (int ni = 0; ni < 4; ++ni)
                cp[ni * 16] = acc[mi][ni][r] + bias0[cc0 + ni * 16] + bias1[cc0 + ni * 16];
        }
    }
}

// ---------------------------------------------------------------------------
// per-row: softmax + argmax(logits+gumbel) + one-hot + sl/ents, then fused
// LSTM pointwise (gates = G + E2G[amax]) writing PACKED h splits + embeds.
template <bool LAST>
__global__ __launch_bounds__(256)
void step_merge(const float* __restrict__ logits, const float* __restrict__ gumbel,
                const float* __restrict__ G, const float* __restrict__ e2g,
                const float* __restrict__ embedding,
                u16* __restrict__ h_hi, u16* __restrict__ h_lo,
                float* __restrict__ c, float* __restrict__ out,
                int* __restrict__ sl, float* __restrict__ ents, int step)
{
    const int b   = blockIdx.x;
    const int tid = threadIdx.x;
    const float* lrow = logits + (size_t)b * V_;
    const float* grow = gumbel + ((size_t)step * B_ + b) * V_;
    __shared__ float lsm[V_];
    __shared__ float red_m[4], red_bv[4], red_s[4], red_t[4];
    __shared__ int   red_bi[4];
    __shared__ float s_M;
    __shared__ int   s_bi;

    float m = -3.4e38f, bv = -3.4e38f;
    int bi = 0x7fffffff;
    for (int q = tid; q < V_ / 4; q += 256) {
        float4 l4 = ((const float4*)lrow)[q];
        float4 g4 = ((const float4*)grow)[q];
        ((float4*)lsm)[q] = l4;
        m = fmaxf(m, fmaxf(fmaxf(l4.x, l4.y), fmaxf(l4.z, l4.w)));
        float p; const int i4 = q * 4;
        p = l4.x + g4.x; if (p > bv) { bv = p; bi = i4; }
        p = l4.y + g4.y; if (p > bv) { bv = p; bi = i4 + 1; }
        p = l4.z + g4.z; if (p > bv) { bv = p; bi = i4 + 2; }
        p = l4.w + g4.w; if (p > bv) { bv = p; bi = i4 + 3; }
    }
#pragma unroll
    for (int off = 32; off > 0; off >>= 1) {
        m = fmaxf(m, __shfl_down(m, off));
        float obv = __shfl_down(bv, off);
        int   obi = __shfl_down(bi, off);
        if (obv > bv || (obv == bv && obi < bi)) { bv = obv; bi = obi; }
    }
    const int wave = tid >> 6, lane = tid & 63;
    if (lane == 0) { red_m[wave] = m; red_bv[wave] = bv; red_bi[wave] = bi; }
    __syncthreads();
    if (tid == 0) {
        m = red_m[0]; bv = red_bv[0]; bi = red_bi[0];
        for (int w = 1; w < 4; ++w) {
            m = fmaxf(m, red_m[w]);
            if (red_bv[w] > bv || (red_bv[w] == bv && red_bi[w] < bi)) {
                bv = red_bv[w]; bi = red_bi[w];
            }
        }
        s_M = m; s_bi = bi;
    }
    __syncthreads();
    const float M = s_M;
    const int amax = s_bi;

    float s = 0.f, t = 0.f;
    for (int q = tid; q < V_; q += 256) {
        const float l = lsm[q];
        const float e = __expf(l - M);
        s += e; t += e * l;
    }
#pragma unroll
    for (int off = 32; off > 0; off >>= 1) {
        s += __shfl_down(s, off);
        t += __shfl_down(t, off);
    }
    if (lane == 0) { red_s[wave] = s; red_t[wave] = t; }

    // zero + one-hot output row (step+1)
    float* orow = out + ((size_t)b * (L_ + 1) + step + 1) * V_;
    const float4 z4 = make_float4(0.f, 0.f, 0.f, 0.f);
    for (int q = tid; q < V_ / 4; q += 256) ((float4*)orow)[q] = z4;
    __syncthreads();
    if (tid == 0) {
        const float ss = red_s[0] + red_s[1] + red_s[2] + red_s[3];
        const float tt = red_t[0] + red_t[1] + red_t[2] + red_t[3];
        ents[b] += (M + logf(ss)) - tt / ss;
        orow[amax] = 1.0f;
        if (amax == EOS_ && sl[b] == INIT_LEN_) sl[b] = step + 2;
    }

    if (!LAST) {
        const float* Gr = G + (size_t)b * H4_;
        const float* er = e2g + (size_t)amax * H4_;
#pragma unroll
        for (int jj = 0; jj < 2; ++jj) {
            const int j = tid + jj * 256;
            const float ig = Gr[j]          + er[j];
            const float fg = Gr[H_ + j]     + er[H_ + j];
            const float gg = Gr[2 * H_ + j] + er[2 * H_ + j];
            const float og = Gr[3 * H_ + j] + er[3 * H_ + j];
            const float si = 1.f / (1.f + expf(-ig));
            const float sf = 1.f / (1.f + expf(-fg));
            const float so = 1.f / (1.f + expf(-og));
            const size_t idx = (size_t)b * H_ + j;
            const float cn = sf * c[idx] + si * tanhf(gg);
            c[idx] = cn;
            const float hv = so * tanhf(cn);
            const u16 hh = f2bf(hv);
            const size_t p = a_pk(b, j);
            h_hi[p] = hh;
            h_lo[p] = f2bf(hv - bf2f(hh));
        }
        if (tid < E_)
            out[OUT_EMB + ((size_t)b * L_ + step + 1) * E_ + tid] =
                embedding[(size_t)amax * E_ + tid];
    }
}

// ---------------------------------------------------------------------------
// W_hh [2048][512] f32 -> packed Bh/Bl (panels 0-15)
__global__ __launch_bounds__(256)
void repack_whh(const float* __restrict__ W_hh, u16* __restrict__ Bh,
                u16* __restrict__ Bl)
{
    const int i = blockIdx.x * 256 + threadIdx.x;   // float4 index
    float4 v = ((const float4*)W_hh)[i];
    const int col = (i * 4) >> 9;
    const int k   = (i * 4) & 511;
    const size_t p = a_pk(col, k);
    const u16 h0 = f2bf(v.x), h1 = f2bf(v.y), h2 = f2bf(v.z), h3 = f2bf(v.w);
    *(ushort4*)(Bh + p) = make_ushort4(h0, h1, h2, h3);
    *(ushort4*)(Bl + p) = make_ushort4(f2bf(v.x - bf2f(h0)), f2bf(v.y - bf2f(h1)),
                                       f2bf(v.z - bf2f(h2)), f2bf(v.w - bf2f(h3)));
}

// W_out [512][4096] f32 (transposed) -> packed Bh/Bl rows 2048..6143
__global__ __launch_bounds__(256)
void repack_wout(const float* __restrict__ W_out, u16* __restrict__ Bh,
                 u16* __restrict__ Bl)
{
    __shared__ float t[32][33];
    const int v0 = blockIdx.x * 32, k0 = blockIdx.y * 32;
    const int x = threadIdx.x & 31, y = threadIdx.x >> 5;
    for (int yy = y; yy < 32; yy += 8)
        t[yy][x] = W_out[(size_t)(k0 + yy) * V_ + v0 + x];
    __syncthreads();
    for (int yy = y; yy < 32; yy += 8) {
        const float v = t[x][yy];           // = W_out[k0+x][v0+yy]
        const size_t p = a_pk(2048 + v0 + yy, k0 + x);
        const u16 h = f2bf(v);
        Bh[p] = h;
        Bl[p] = f2bf(v - bf2f(h));
    }
}

// elementwise f32 -> bf16 hi/lo split (emb, W_ih for E2G build, row-major)
__global__ __launch_bounds__(256)
void split_mat(const float* __restrict__ X, u16* __restrict__ hi,
               u16* __restrict__ lo)
{
    const int i = blockIdx.x * 256 + threadIdx.x;
    float4 v = ((const float4*)X)[i];
    const u16 h0 = f2bf(v.x), h1 = f2bf(v.y), h2 = f2bf(v.z), h3 = f2bf(v.w);
    ((ushort4*)hi)[i] = make_ushort4(h0, h1, h2, h3);
    ((ushort4*)lo)[i] = make_ushort4(f2bf(v.x - bf2f(h0)), f2bf(v.y - bf2f(h1)),
                                     f2bf(v.z - bf2f(h2)), f2bf(v.w - bf2f(h3)));
}

// h0 = hidden_state @ W_in + b_in -> packed Ah/Al; c0 = 0
__global__ __launch_bounds__(256)
void h0_kernel(const float* __restrict__ hs, const float* __restrict__ W_in,
               const float* __restrict__ b_in, u16* __restrict__ Ah,
               u16* __restrict__ Al, float* __restrict__ c)
{
    const int idx = blockIdx.x * 256 + threadIdx.x;
    const int b = idx >> 9, j = idx & 511;
    float acc = b_in[j];
#pragma unroll
    for (int e = 0; e < META_; ++e)
        acc = fmaf(hs[b * META_ + e], W_in[e * H_ + j], acc);
    const u16 hh = f2bf(acc);
    const size_t p = a_pk(b, j);
    Ah[p] = hh;
    Al[p] = f2bf(acc - bf2f(hh));
    c[idx] = 0.f;
}

__global__ __launch_bounds__(256)
void init_outputs(float* __restrict__ out, int* __restrict__ tok,
                  int* __restrict__ sl, float* __restrict__ ents)
{
    const int tid = blockIdx.x * 256 + threadIdx.x;
    {
        const int b = tid >> 10;
        const int q = tid & 1023;
        float4 z = make_float4(0.f, 0.f, 0.f, 0.f);
        if (q == 0) z.x = 1.0f;           // SOS = 0
        ((float4*)out)[(size_t)b * ((L_ + 1) * V_ / 4) + q] = z;
    }
    for (size_t t = tid; t < (size_t)B_ * V_; t += (size_t)gridDim.x * 256)
        out[OUT_SP + t] = 0.f;
    if (tid < B_) { tok[tid] = 0; sl[tid] = INIT_LEN_; ents[tid] = 0.f; }
}

// LSTM pointwise for the PRE-LOOP step only (tok=0): gates = G + E2G[tok]
__global__ __launch_bounds__(256)
void lstm_cell(const float* __restrict__ G, const float* __restrict__ e2g,
               u16* __restrict__ Ah, u16* __restrict__ Al,
               float* __restrict__ c, const float* __restrict__ embedding,
               const int* __restrict__ tok, float* __restrict__ out, int step)
{
    const int idx = blockIdx.x * 256 + threadIdx.x;   // B*H
    const int b = idx >> 9, j = idx & 511;
    const size_t g0 = (size_t)b * H4_;
    const size_t e0 = (size_t)tok[b] * H4_;
    const float ig = G[g0 + j]          + e2g[e0 + j];
    const float fg = G[g0 + H_ + j]     + e2g[e0 + H_ + j];
    const float gg = G[g0 + 2 * H_ + j] + e2g[e0 + 2 * H_ + j];
    const float og = G[g0 + 3 * H_ + j] + e2g[e0 + 3 * H_ + j];
    const float si = 1.f / (1.f + expf(-ig));
    const float sf = 1.f / (1.f + expf(-fg));
    const float so = 1.f / (1.f + expf(-og));
    const float cn = sf * c[idx] + si * tanhf(gg);
    c[idx] = cn;
    const float hv = so * tanhf(cn);
    const u16 hh = f2bf(hv);
    const size_t p = a_pk(b, j);
    Ah[p] = hh;
    Al[p] = f2bf(hv - bf2f(hh));
    if (j < E_)
        out[OUT_EMB + ((size_t)b * L_ + step) * E_ + j] =
            embedding[(size_t)tok[b] * E_ + j];
}

__global__ __launch_bounds__(256)
void finalize(const int* __restrict__ sl, const float* __restrict__ ents,
              float* __restrict__ out)
{
    const int tid = threadIdx.x;
    float s = 0.f;
    for (int b = tid; b < B_; b += 256) {
        s += ents[b];
        out[OUT_SL + b] = (float)sl[b];
    }
    __shared__ float red[4];
#pragma unroll
    for (int off = 32; off > 0; off >>= 1) s += __shfl_down(s, off);
    if ((tid & 63) == 0) red[tid >> 6] = s;
    __syncthreads();
    if (tid == 0)
        out[OUT_ENT] = (red[0] + red[1] + red[2] + red[3]) / (float)B_ / (float)L_;
}

// ---------------------------------------------------------------------------
extern "C" void kernel_launch(void* const* d_in, const int* in_sizes, int n_in,
                              void* d_out, int out_size, void* d_ws, size_t ws_size,
                              hipStream_t stream)
{
    const float* hidden    = (const float*)d_in[0];
    const float* W_in      = (const float*)d_in[1];
    const float* b_in      = (const float*)d_in[2];
    const float* embedding = (const float*)d_in[3];
    const float* W_ih      = (const float*)d_in[4];
    const float* W_hh      = (const float*)d_in[5];
    const float* b_ih      = (const float*)d_in[6];
    const float* b_hh      = (const float*)d_in[7];
    const float* W_out     = (const float*)d_in[8];
    const float* b_out     = (const float*)d_in[9];
    const float* gumbel    = (const float*)d_in[10];
    float* out = (float*)d_out;

    float* ws    = (float*)d_ws;
    float* E2G   = ws + WS_E2G;
    float* logit = ws + WS_LOGITS;
    float* G     = ws + WS_G;
    float* c     = ws + WS_C;
    u16*   wsu   = (u16*)(ws + WS_F32_END);
    u16* Bh_pk   = wsu + U_BH;
    u16* Bl_pk   = wsu + U_BL;
    u16* Ah_pk   = wsu + U_AH;
    u16* Al_pk   = wsu + U_AL;
    int* tok     = (int*)(wsu + U_END);
    int* sl      = tok + B_;
    float* ents  = (float*)(sl + B_);
    // emb/wih bf16 splits overlay the LOGITS region (dead after E2G build)
    u16* emb_hi  = (u16*)logit;
    u16* emb_lo  = emb_hi + (size_t)V_ * E_;
    u16* wih_hi  = emb_lo + (size_t)V_ * E_;
    u16* wih_lo  = wih_hi + (size_t)H4_ * E_;

    // ---- one-time per call ----
    repack_whh<<<(H4_ * H_ / 4) / 256, 256, 0, stream>>>(W_hh, Bh_pk, Bl_pk);
    repack_wout<<<dim3(V_ / 32, H_ / 32), 256, 0, stream>>>(W_out, Bh_pk, Bl_pk);
    split_mat<<<(V_ * E_ / 4) / 256, 256, 0, stream>>>(embedding, emb_hi, emb_lo);
    split_mat<<<(H4_ * E_ / 4) / 256, 256, 0, stream>>>(W_ih, wih_hi, wih_lo);
    h0_kernel<<<(B_ * H_) / 256, 256, 0, stream>>>(hidden, W_in, b_in,
                                                   Ah_pk, Al_pk, c);
    init_outputs<<<(B_ * V_ / 4) / 256, 256, 0, stream>>>(out, tok, sl, ents);
    // E2G = embedding @ W_ih^T + b_ih + b_hh   [V, 4H]  (old 16x16 kernel)
    gemm_e2g<<<dim3(H4_ / 128, V_ / 128), 256, 0, stream>>>(
        emb_hi, emb_lo, wih_hi, wih_lo, E2G, E_, b_ih, b_hh);
    // G0 = h0 @ W_hh^T  (gates panels only)
    gemm32<<<dim3(16, 16), 256, 0, stream>>>(Ah_pk, Al_pk, Bh_pk, Bl_pk,
                                             G, logit, b_out, 0);
    // pointwise step 0 (tok=0) -> h1, embeds row 0
    lstm_cell<<<(B_ * H_) / 256, 256, 0, stream>>>(G, E2G, Ah_pk, Al_pk, c,
                                                   embedding, tok, out, 0);

    for (int i = 0; i < L_; ++i) {
        if (i < L_ - 1) {
            // [G_{i+1} | logits_i] = h_{i+1} @ [W_hh | WoutT]^T
            gemm32<<<dim3(48, 16), 256, 0, stream>>>(
                Ah_pk, Al_pk, Bh_pk, Bl_pk, G, logit, b_out, 0);
            step_merge<false><<<B_, 256, 0, stream>>>(
                logit, gumbel, G, E2G, embedding, Ah_pk, Al_pk, c, out,
                sl, ents, i);
        } else {
            // logits only
            gemm32<<<dim3(32, 16), 256, 0, stream>>>(
                Ah_pk, Al_pk, Bh_pk, Bl_pk, G, logit, b_out, 16);
            step_merge<true><<<B_, 256, 0, stream>>>(
                logit, gumbel, G, E2G, embedding, Ah_pk, Al_pk, c, out,
                sl, ents, i);
        }
    }
    finalize<<<1, 256, 0, stream>>>(sl, ents, out);
}